// Round 1
// baseline (1515.361 us; speedup 1.0000x reference)
//
#include <hip/hip_runtime.h>
#include <hip/hip_bf16.h>
#include <math.h>

// Problem constants
#define D_MODEL 1024
#define D_STATE 16
#define D_CONV 4
#define D_INNER 2048
#define BATCH 2
#define SEQ 4096
#define NROW (BATCH * SEQ)          // 8192 rows (b*L + t)
#define LN_EPS 1e-5f

// ---------------------------------------------------------------------------
// 1. LayerNorm: one block per row of 1024 floats. float4 loads, shfl+LDS reduce.
// ---------------------------------------------------------------------------
__global__ __launch_bounds__(256) void ln_kernel(const float* __restrict__ x,
                                                 const float* __restrict__ gamma,
                                                 const float* __restrict__ beta,
                                                 float* __restrict__ xn) {
    const int row = blockIdx.x;
    const int tid = threadIdx.x;
    const float4* xr = reinterpret_cast<const float4*>(x + (size_t)row * D_MODEL);
    float4 v = xr[tid];

    __shared__ float red[8];
    const int lane = tid & 63, wave = tid >> 6;

    // mean
    float s = v.x + v.y + v.z + v.w;
    #pragma unroll
    for (int off = 32; off > 0; off >>= 1) s += __shfl_down(s, off, 64);
    if (lane == 0) red[wave] = s;
    __syncthreads();
    float mu = (red[0] + red[1] + red[2] + red[3]) * (1.0f / D_MODEL);
    __syncthreads();

    // variance
    float dx = v.x - mu, dy = v.y - mu, dz = v.z - mu, dw = v.w - mu;
    float ss = dx * dx + dy * dy + dz * dz + dw * dw;
    #pragma unroll
    for (int off = 32; off > 0; off >>= 1) ss += __shfl_down(ss, off, 64);
    if (lane == 0) red[wave] = ss;
    __syncthreads();
    float var = (red[0] + red[1] + red[2] + red[3]) * (1.0f / D_MODEL);
    float rs = rsqrtf(var + LN_EPS);

    const float4 gv = reinterpret_cast<const float4*>(gamma)[tid];
    const float4 bv = reinterpret_cast<const float4*>(beta)[tid];
    float4 o;
    o.x = dx * rs * gv.x + bv.x;
    o.y = dy * rs * gv.y + bv.y;
    o.z = dz * rs * gv.z + bv.z;
    o.w = dw * rs * gv.w + bv.w;
    reinterpret_cast<float4*>(xn + (size_t)row * D_MODEL)[tid] = o;
}

// ---------------------------------------------------------------------------
// 2. Tiled fp32 GEMM (TN): C[M,N] = A[M,K] * B[N,K]^T (+ add), all row-major.
//    128x128 tile, BK=16, 256 threads, 8x8 per-thread micro-tile.
// ---------------------------------------------------------------------------
#define GT_BM 128
#define GT_BN 128
#define GT_BK 16
#define GT_LDP (GT_BM + 4)   // padded leading dim (floats); 528B rows keep 16B align

__global__ __launch_bounds__(256) void gemm_tn(const float* __restrict__ A,
                                               const float* __restrict__ B,
                                               const float* __restrict__ add,
                                               float* __restrict__ C,
                                               int M, int N, int K) {
    __shared__ float As[GT_BK][GT_LDP];
    __shared__ float Bs[GT_BK][GT_LDP];

    const int tid = threadIdx.x;
    const int row0 = blockIdx.y * GT_BM;
    const int col0 = blockIdx.x * GT_BN;

    // staging: each thread loads 8 floats (2x float4) of A and of B
    const int lr = tid >> 1;            // 0..127 tile row
    const int lk = (tid & 1) * 8;       // 0 or 8

    const int ty = tid >> 4;            // 0..15
    const int tx = tid & 15;            // 0..15

    float acc[8][8];
    #pragma unroll
    for (int i = 0; i < 8; ++i)
        #pragma unroll
        for (int j = 0; j < 8; ++j) acc[i][j] = 0.0f;

    for (int k0 = 0; k0 < K; k0 += GT_BK) {
        float4 a0 = *reinterpret_cast<const float4*>(&A[(size_t)(row0 + lr) * K + k0 + lk]);
        float4 a1 = *reinterpret_cast<const float4*>(&A[(size_t)(row0 + lr) * K + k0 + lk + 4]);
        float4 b0 = *reinterpret_cast<const float4*>(&B[(size_t)(col0 + lr) * K + k0 + lk]);
        float4 b1 = *reinterpret_cast<const float4*>(&B[(size_t)(col0 + lr) * K + k0 + lk + 4]);
        As[lk + 0][lr] = a0.x; As[lk + 1][lr] = a0.y; As[lk + 2][lr] = a0.z; As[lk + 3][lr] = a0.w;
        As[lk + 4][lr] = a1.x; As[lk + 5][lr] = a1.y; As[lk + 6][lr] = a1.z; As[lk + 7][lr] = a1.w;
        Bs[lk + 0][lr] = b0.x; Bs[lk + 1][lr] = b0.y; Bs[lk + 2][lr] = b0.z; Bs[lk + 3][lr] = b0.w;
        Bs[lk + 4][lr] = b1.x; Bs[lk + 5][lr] = b1.y; Bs[lk + 6][lr] = b1.z; Bs[lk + 7][lr] = b1.w;
        __syncthreads();

        #pragma unroll
        for (int kk = 0; kk < GT_BK; ++kk) {
            float4 av0 = *reinterpret_cast<const float4*>(&As[kk][ty * 8]);
            float4 av1 = *reinterpret_cast<const float4*>(&As[kk][ty * 8 + 4]);
            float4 bv0 = *reinterpret_cast<const float4*>(&Bs[kk][tx * 8]);
            float4 bv1 = *reinterpret_cast<const float4*>(&Bs[kk][tx * 8 + 4]);
            float a[8] = {av0.x, av0.y, av0.z, av0.w, av1.x, av1.y, av1.z, av1.w};
            float b[8] = {bv0.x, bv0.y, bv0.z, bv0.w, bv1.x, bv1.y, bv1.z, bv1.w};
            #pragma unroll
            for (int i = 0; i < 8; ++i)
                #pragma unroll
                for (int j = 0; j < 8; ++j)
                    acc[i][j] = fmaf(a[i], b[j], acc[i][j]);
        }
        __syncthreads();
    }

    // epilogue: optional residual add, float4 stores
    #pragma unroll
    for (int i = 0; i < 8; ++i) {
        const int r = row0 + ty * 8 + i;
        const int c = col0 + tx * 8;
        float4 v0 = make_float4(acc[i][0], acc[i][1], acc[i][2], acc[i][3]);
        float4 v1 = make_float4(acc[i][4], acc[i][5], acc[i][6], acc[i][7]);
        if (add) {
            float4 x0 = *reinterpret_cast<const float4*>(&add[(size_t)r * N + c]);
            float4 x1 = *reinterpret_cast<const float4*>(&add[(size_t)r * N + c + 4]);
            v0.x += x0.x; v0.y += x0.y; v0.z += x0.z; v0.w += x0.w;
            v1.x += x1.x; v1.y += x1.y; v1.z += x1.z; v1.w += x1.w;
        }
        *reinterpret_cast<float4*>(&C[(size_t)r * N + c]) = v0;
        *reinterpret_cast<float4*>(&C[(size_t)r * N + c + 4]) = v1;
    }
}

// ---------------------------------------------------------------------------
// 3. V[r, s] = sum_i x_part[r, i] * Bm[s, i]   (x_part = xz cols 0..2047)
//    One block (256 thr) per row.
// ---------------------------------------------------------------------------
__global__ __launch_bounds__(256) void v_kernel(const float* __restrict__ xz,
                                                const float* __restrict__ Bm,
                                                float* __restrict__ V) {
    const int r = blockIdx.x;
    const int tid = threadIdx.x;
    const float* u = xz + (size_t)r * (2 * D_INNER);

    float acc[D_STATE];
    #pragma unroll
    for (int s = 0; s < D_STATE; ++s) acc[s] = 0.0f;

    for (int i = tid; i < D_INNER; i += 256) {
        float uv = u[i];
        #pragma unroll
        for (int s = 0; s < D_STATE; ++s)
            acc[s] = fmaf(uv, Bm[s * D_INNER + i], acc[s]);
    }

    #pragma unroll
    for (int s = 0; s < D_STATE; ++s)
        #pragma unroll
        for (int off = 32; off > 0; off >>= 1)
            acc[s] += __shfl_down(acc[s], off, 64);

    __shared__ float red[4][D_STATE];
    const int lane = tid & 63, wave = tid >> 6;
    if (lane == 0) {
        #pragma unroll
        for (int s = 0; s < D_STATE; ++s) red[wave][s] = acc[s];
    }
    __syncthreads();
    if (tid < D_STATE) {
        float v = red[0][tid] + red[1][tid] + red[2][tid] + red[3][tid];
        V[(size_t)r * D_STATE + tid] = v;
    }
}

// ---------------------------------------------------------------------------
// 4. Sequential scan: state_t = state_{t-1} @ A^T + V_t ; S_t = state_t.
//    One block of 64 threads (single wave). Lanes 0..31 own (b, s).
//    Fast path when A == I (true for these inputs); general path via shfl.
// ---------------------------------------------------------------------------
#define SCAN_CHUNK 256

__global__ __launch_bounds__(64) void scan_kernel(const float* __restrict__ V,
                                                  const float* __restrict__ A,
                                                  float* __restrict__ S) {
    __shared__ float Al[D_STATE * D_STATE];
    __shared__ float Vl[2 * SCAN_CHUNK * D_STATE];   // 32 KB
    __shared__ float Sl[2 * SCAN_CHUNK * D_STATE];   // 32 KB
    __shared__ int nid;

    const int tid = threadIdx.x;
    if (tid == 0) nid = 0;
    __syncthreads();
    for (int i = tid; i < D_STATE * D_STATE; i += 64) {
        float a = A[i];
        Al[i] = a;
        float ex = ((i >> 4) == (i & 15)) ? 1.0f : 0.0f;
        if (a != ex) atomicOr(&nid, 1);
    }
    __syncthreads();
    const bool general = (nid != 0);

    float st = 0.0f;
    const int bb = (tid >> 4) & 1;   // for tid<32
    const int ss = tid & 15;

    for (int t0 = 0; t0 < SEQ; t0 += SCAN_CHUNK) {
        // load V chunk for both batches: flat idx = b*CHUNK*16 + tl*16 + s
        for (int idx = tid; idx < 2 * SCAN_CHUNK * D_STATE; idx += 64) {
            int b = idx >> 12;              // SCAN_CHUNK*16 = 4096
            int rem = idx & 4095;
            Vl[idx] = V[((size_t)(b * SEQ + t0) * D_STATE) + rem];
        }
        __syncthreads();

        if (tid < 32) {
            float* vb = Vl + bb * SCAN_CHUNK * D_STATE + ss;
            float* sb = Sl + bb * SCAN_CHUNK * D_STATE + ss;
            if (!general) {
                #pragma unroll 8
                for (int t = 0; t < SCAN_CHUNK; ++t) {
                    st += vb[t * D_STATE];
                    sb[t * D_STATE] = st;
                }
            } else {
                for (int t = 0; t < SCAN_CHUNK; ++t) {
                    float ns = vb[t * D_STATE];
                    #pragma unroll
                    for (int s2 = 0; s2 < D_STATE; ++s2) {
                        float other = __shfl(st, (tid & 16) | s2, 64);
                        ns = fmaf(Al[ss * D_STATE + s2], other, ns);
                    }
                    st = ns;
                    sb[t * D_STATE] = st;
                }
            }
        }
        __syncthreads();

        for (int idx = tid; idx < 2 * SCAN_CHUNK * D_STATE; idx += 64) {
            int b = idx >> 12;
            int rem = idx & 4095;
            S[((size_t)(b * SEQ + t0) * D_STATE) + rem] = Sl[idx];
        }
        __syncthreads();
    }
}

// ---------------------------------------------------------------------------
// 5. y = (silu(depthwise_causal_conv(x_part) ) + S @ Cm) * sigmoid(z)
//    One thread per (row, i) element.
// ---------------------------------------------------------------------------
__global__ __launch_bounds__(256) void y_kernel(const float* __restrict__ xz,
                                                const float* __restrict__ S,
                                                const float* __restrict__ Cm,
                                                const float* __restrict__ convw,
                                                const float* __restrict__ convb,
                                                float* __restrict__ y) {
    const int gid = blockIdx.x * 256 + threadIdx.x;  // over NROW * D_INNER
    const int r = gid >> 11;       // row index (b*L + t)
    const int i = gid & (D_INNER - 1);
    const int t = r & (SEQ - 1);

    const float4 w = *reinterpret_cast<const float4*>(&convw[i * D_CONV]);
    const float* xp = xz + (size_t)r * (2 * D_INNER) + i;   // x_part column i

    float acc = convb[i];
    if (t >= 3) {
        acc = fmaf(w.x, xp[-3 * 2 * D_INNER], acc);
        acc = fmaf(w.y, xp[-2 * 2 * D_INNER], acc);
        acc = fmaf(w.z, xp[-1 * 2 * D_INNER], acc);
        acc = fmaf(w.w, xp[0], acc);
    } else {
        acc = fmaf(w.w, xp[0], acc);
        if (t >= 1) acc = fmaf(w.z, xp[-1 * 2 * D_INNER], acc);
        if (t >= 2) acc = fmaf(w.y, xp[-2 * 2 * D_INNER], acc);
    }
    const float xc = acc / (1.0f + expf(-acc));   // silu

    float sc = 0.0f;
    const float* Sr = S + (size_t)r * D_STATE;
    #pragma unroll
    for (int s = 0; s < D_STATE; ++s)
        sc = fmaf(Sr[s], Cm[s * D_INNER + i], sc);

    const float zv = xz[(size_t)r * (2 * D_INNER) + D_INNER + i];
    const float sg = 1.0f / (1.0f + expf(-zv));
    y[(size_t)r * D_INNER + i] = (xc + sc) * sg;
}

// ---------------------------------------------------------------------------
// launch
// ---------------------------------------------------------------------------
extern "C" void kernel_launch(void* const* d_in, const int* in_sizes, int n_in,
                              void* d_out, int out_size, void* d_ws, size_t ws_size,
                              hipStream_t stream) {
    const float* x      = (const float*)d_in[0];
    const float* ln_g   = (const float*)d_in[1];
    const float* ln_b   = (const float*)d_in[2];
    const float* W_in   = (const float*)d_in[3];
    const float* conv_w = (const float*)d_in[4];
    const float* conv_b = (const float*)d_in[5];
    const float* W_out  = (const float*)d_in[6];
    const float* A      = (const float*)d_in[7];
    const float* Bm     = (const float*)d_in[8];
    const float* Cm     = (const float*)d_in[9];
    float* out = (float*)d_out;

    float* ws = (float*)d_ws;
    float* xn = ws;                                    // 8192*1024
    float* xz = xn + (size_t)NROW * D_MODEL;           // 8192*4096
    float* V  = xz + (size_t)NROW * 2 * D_INNER;       // 8192*16
    float* S  = V  + (size_t)NROW * D_STATE;           // 8192*16
    float* y  = S  + (size_t)NROW * D_STATE;           // 8192*2048

    // 1. LayerNorm
    ln_kernel<<<NROW, 256, 0, stream>>>(x, ln_g, ln_b, xn);

    // 2. xz = xn @ W_in^T   (M=8192, N=4096, K=1024)
    gemm_tn<<<dim3((2 * D_INNER) / GT_BN, NROW / GT_BM), 256, 0, stream>>>(
        xn, W_in, nullptr, xz, NROW, 2 * D_INNER, D_MODEL);

    // 3. V = x_part @ Bm^T
    v_kernel<<<NROW, 256, 0, stream>>>(xz, Bm, V);

    // 4. sequential scan -> S
    scan_kernel<<<1, 64, 0, stream>>>(V, A, S);

    // 5. y = (silu(conv(x_part)) + S@Cm) * sigmoid(z)
    y_kernel<<<(NROW * D_INNER) / 256, 256, 0, stream>>>(xz, S, Cm, conv_w, conv_b, y);

    // 6. out = x + y @ W_out^T  (M=8192, N=1024, K=2048)
    gemm_tn<<<dim3(D_MODEL / GT_BN, NROW / GT_BM), 256, 0, stream>>>(
        y, W_out, x, out, NROW, D_MODEL, D_INNER);
}

// Round 2
// 510.239 us; speedup vs baseline: 2.9699x; 2.9699x over previous
//
#include <hip/hip_runtime.h>
#include <hip/hip_bf16.h>
#include <math.h>

// Problem constants
#define D_MODEL 1024
#define D_STATE 16
#define D_CONV 4
#define D_INNER 2048
#define BATCH 2
#define SEQ 4096
#define NROW (BATCH * SEQ)          // 8192 rows (b*L + t)
#define LN_EPS 1e-5f

typedef __attribute__((ext_vector_type(8))) short  bf16x8_t;   // 8 bf16 (4 VGPRs)
typedef __attribute__((ext_vector_type(4))) float  f32x4_t;    // MFMA accumulator
typedef __attribute__((ext_vector_type(8))) unsigned short u16x8_t;

// round-to-nearest-even f32 -> bf16 (no NaN handling; data is finite)
__device__ inline unsigned short f2bf(float f) {
    unsigned u = __float_as_uint(f);
    u += 0x7fffu + ((u >> 16) & 1u);
    return (unsigned short)(u >> 16);
}

#define GLL16(g, l)                                                            \
    __builtin_amdgcn_global_load_lds(                                          \
        (const __attribute__((address_space(1))) void*)(g),                    \
        (__attribute__((address_space(3))) void*)(l), 16, 0, 0)

// ---------------------------------------------------------------------------
// 0. fp32 -> bf16 conversion (8 elements / thread)
// ---------------------------------------------------------------------------
__global__ __launch_bounds__(256) void cvt_bf16(const float* __restrict__ in,
                                                unsigned short* __restrict__ out) {
    const int i = blockIdx.x * 256 + threadIdx.x;   // i-th group of 8
    const float4 a = reinterpret_cast<const float4*>(in)[2 * i];
    const float4 b = reinterpret_cast<const float4*>(in)[2 * i + 1];
    u16x8_t p;
    p[0] = f2bf(a.x); p[1] = f2bf(a.y); p[2] = f2bf(a.z); p[3] = f2bf(a.w);
    p[4] = f2bf(b.x); p[5] = f2bf(b.y); p[6] = f2bf(b.z); p[7] = f2bf(b.w);
    reinterpret_cast<u16x8_t*>(out)[i] = p;
}

// ---------------------------------------------------------------------------
// 1. LayerNorm: one block per row of 1024 floats -> bf16 output
// ---------------------------------------------------------------------------
__global__ __launch_bounds__(256) void ln_kernel(const float* __restrict__ x,
                                                 const float* __restrict__ gamma,
                                                 const float* __restrict__ beta,
                                                 unsigned short* __restrict__ xn) {
    const int row = blockIdx.x;
    const int tid = threadIdx.x;
    const float4* xr = reinterpret_cast<const float4*>(x + (size_t)row * D_MODEL);
    float4 v = xr[tid];

    __shared__ float red[8];
    const int lane = tid & 63, wave = tid >> 6;

    float s = v.x + v.y + v.z + v.w;
    #pragma unroll
    for (int off = 32; off > 0; off >>= 1) s += __shfl_down(s, off, 64);
    if (lane == 0) red[wave] = s;
    __syncthreads();
    float mu = (red[0] + red[1] + red[2] + red[3]) * (1.0f / D_MODEL);
    __syncthreads();

    float dx = v.x - mu, dy = v.y - mu, dz = v.z - mu, dw = v.w - mu;
    float ss = dx * dx + dy * dy + dz * dz + dw * dw;
    #pragma unroll
    for (int off = 32; off > 0; off >>= 1) ss += __shfl_down(ss, off, 64);
    if (lane == 0) red[wave] = ss;
    __syncthreads();
    float var = (red[0] + red[1] + red[2] + red[3]) * (1.0f / D_MODEL);
    float rs = rsqrtf(var + LN_EPS);

    const float4 gv = reinterpret_cast<const float4*>(gamma)[tid];
    const float4 bv = reinterpret_cast<const float4*>(beta)[tid];
    ushort4 o;
    o.x = f2bf(dx * rs * gv.x + bv.x);
    o.y = f2bf(dy * rs * gv.y + bv.y);
    o.z = f2bf(dz * rs * gv.z + bv.z);
    o.w = f2bf(dw * rs * gv.w + bv.w);
    reinterpret_cast<ushort4*>(xn + (size_t)row * D_MODEL)[tid] = o;
}

// ---------------------------------------------------------------------------
// 2. bf16 MFMA GEMM (TN): C[M,N] = A[M,K] * B[N,K]^T (+ add), fp32 out.
//    m97 structure: 128x128 tile, BK=32, 4 waves, global_load_lds w=16,
//    16x16x32 MFMA, 4x4 fragments/wave.
// ---------------------------------------------------------------------------
__global__ __launch_bounds__(256) void gemm_bf16(const short* __restrict__ A,
                                                 const short* __restrict__ B,
                                                 const float* __restrict__ add,
                                                 float* __restrict__ C,
                                                 int M, int N, int K) {
    __shared__ short As[128 * 32];
    __shared__ short Bs[128 * 32];

    const int tid = threadIdx.x;
    const int w = tid >> 6;          // wave 0..3
    const int l = tid & 63;          // lane
    const int row0 = blockIdx.y * 128;
    const int col0 = blockIdx.x * 128;
    const int wr = (w >> 1) * 64;    // wave's 64x64 sub-tile
    const int wc = (w & 1) * 64;

    f32x4_t acc[4][4] = {};

    // staging: each wave covers 32 rows of A and 32 rows of B per K-step,
    // two global_load_lds(16B) each (16 rows per call).
    const int srow = w * 32 + (l >> 2);
    const int scol = (l & 3) * 8;
    const short* aSrc = A + (size_t)(row0 + srow) * K + scol;
    const short* bSrc = B + (size_t)(col0 + srow) * K + scol;
    const size_t rstep = (size_t)16 * K;

    const int fr = l & 15;           // fragment row (A) / col (B)
    const int fk = (l >> 4) * 8;     // fragment k offset

    for (int k0 = 0; k0 < K; k0 += 32) {
        GLL16(aSrc + k0,         &As[(w * 32) * 32]);
        GLL16(aSrc + k0 + rstep, &As[(w * 32 + 16) * 32]);
        GLL16(bSrc + k0,         &Bs[(w * 32) * 32]);
        GLL16(bSrc + k0 + rstep, &Bs[(w * 32 + 16) * 32]);
        __syncthreads();

        bf16x8_t af[4], bfr[4];
        #pragma unroll
        for (int m = 0; m < 4; ++m)
            af[m] = *reinterpret_cast<const bf16x8_t*>(&As[(wr + m * 16 + fr) * 32 + fk]);
        #pragma unroll
        for (int n = 0; n < 4; ++n)
            bfr[n] = *reinterpret_cast<const bf16x8_t*>(&Bs[(wc + n * 16 + fr) * 32 + fk]);

        #pragma unroll
        for (int m = 0; m < 4; ++m)
            #pragma unroll
            for (int n = 0; n < 4; ++n)
                acc[m][n] = __builtin_amdgcn_mfma_f32_16x16x32_bf16(
                    af[m], bfr[n], acc[m][n], 0, 0, 0);
        __syncthreads();
    }

    // epilogue: C/D layout col=lane&15, row=(lane>>4)*4+j  [m89-verified]
    const int cr = (l >> 4) * 4;
    const int cc = l & 15;
    #pragma unroll
    for (int m = 0; m < 4; ++m) {
        #pragma unroll
        for (int n = 0; n < 4; ++n) {
            size_t base = (size_t)(row0 + wr + m * 16 + cr) * N + (col0 + wc + n * 16 + cc);
            #pragma unroll
            for (int j = 0; j < 4; ++j) {
                float v = acc[m][n][j];
                if (add) v += add[base + (size_t)j * N];
                C[base + (size_t)j * N] = v;
            }
        }
    }
}

// ---------------------------------------------------------------------------
// 3. V[r, s] = sum_i x_part[r, i] * Bm[s, i]
// ---------------------------------------------------------------------------
__global__ __launch_bounds__(256) void v_kernel(const float* __restrict__ xz,
                                                const float* __restrict__ Bm,
                                                float* __restrict__ V) {
    const int r = blockIdx.x;
    const int tid = threadIdx.x;
    const float* u = xz + (size_t)r * (2 * D_INNER);

    float acc[D_STATE];
    #pragma unroll
    for (int s = 0; s < D_STATE; ++s) acc[s] = 0.0f;

    for (int i = tid; i < D_INNER; i += 256) {
        float uv = u[i];
        #pragma unroll
        for (int s = 0; s < D_STATE; ++s)
            acc[s] = fmaf(uv, Bm[s * D_INNER + i], acc[s]);
    }

    #pragma unroll
    for (int s = 0; s < D_STATE; ++s)
        #pragma unroll
        for (int off = 32; off > 0; off >>= 1)
            acc[s] += __shfl_down(acc[s], off, 64);

    __shared__ float red[4][D_STATE];
    const int lane = tid & 63, wave = tid >> 6;
    if (lane == 0) {
        #pragma unroll
        for (int s = 0; s < D_STATE; ++s) red[wave][s] = acc[s];
    }
    __syncthreads();
    if (tid < D_STATE) {
        float v = red[0][tid] + red[1][tid] + red[2][tid] + red[3][tid];
        V[(size_t)r * D_STATE + tid] = v;
    }
}

// ---------------------------------------------------------------------------
// 4. Sequential scan (unchanged)
// ---------------------------------------------------------------------------
#define SCAN_CHUNK 256

__global__ __launch_bounds__(64) void scan_kernel(const float* __restrict__ V,
                                                  const float* __restrict__ A,
                                                  float* __restrict__ S) {
    __shared__ float Al[D_STATE * D_STATE];
    __shared__ float Vl[2 * SCAN_CHUNK * D_STATE];
    __shared__ float Sl[2 * SCAN_CHUNK * D_STATE];
    __shared__ int nid;

    const int tid = threadIdx.x;
    if (tid == 0) nid = 0;
    __syncthreads();
    for (int i = tid; i < D_STATE * D_STATE; i += 64) {
        float a = A[i];
        Al[i] = a;
        float ex = ((i >> 4) == (i & 15)) ? 1.0f : 0.0f;
        if (a != ex) atomicOr(&nid, 1);
    }
    __syncthreads();
    const bool general = (nid != 0);

    float st = 0.0f;
    const int bb = (tid >> 4) & 1;
    const int ss = tid & 15;

    for (int t0 = 0; t0 < SEQ; t0 += SCAN_CHUNK) {
        for (int idx = tid; idx < 2 * SCAN_CHUNK * D_STATE; idx += 64) {
            int b = idx >> 12;
            int rem = idx & 4095;
            Vl[idx] = V[((size_t)(b * SEQ + t0) * D_STATE) + rem];
        }
        __syncthreads();

        if (tid < 32) {
            float* vb = Vl + bb * SCAN_CHUNK * D_STATE + ss;
            float* sb = Sl + bb * SCAN_CHUNK * D_STATE + ss;
            if (!general) {
                #pragma unroll 8
                for (int t = 0; t < SCAN_CHUNK; ++t) {
                    st += vb[t * D_STATE];
                    sb[t * D_STATE] = st;
                }
            } else {
                for (int t = 0; t < SCAN_CHUNK; ++t) {
                    float ns = vb[t * D_STATE];
                    #pragma unroll
                    for (int s2 = 0; s2 < D_STATE; ++s2) {
                        float other = __shfl(st, (tid & 16) | s2, 64);
                        ns = fmaf(Al[ss * D_STATE + s2], other, ns);
                    }
                    st = ns;
                    sb[t * D_STATE] = st;
                }
            }
        }
        __syncthreads();

        for (int idx = tid; idx < 2 * SCAN_CHUNK * D_STATE; idx += 64) {
            int b = idx >> 12;
            int rem = idx & 4095;
            S[((size_t)(b * SEQ + t0) * D_STATE) + rem] = Sl[idx];
        }
        __syncthreads();
    }
}

// ---------------------------------------------------------------------------
// 5. y = (silu(conv(x_part)) + S @ Cm) * sigmoid(z)  -> bf16 output
// ---------------------------------------------------------------------------
__global__ __launch_bounds__(256) void y_kernel(const float* __restrict__ xz,
                                                const float* __restrict__ S,
                                                const float* __restrict__ Cm,
                                                const float* __restrict__ convw,
                                                const float* __restrict__ convb,
                                                unsigned short* __restrict__ y) {
    const int gid = blockIdx.x * 256 + threadIdx.x;
    const int r = gid >> 11;
    const int i = gid & (D_INNER - 1);
    const int t = r & (SEQ - 1);

    const float4 w = *reinterpret_cast<const float4*>(&convw[i * D_CONV]);
    const float* xp = xz + (size_t)r * (2 * D_INNER) + i;

    float acc = convb[i];
    if (t >= 3) {
        acc = fmaf(w.x, xp[-3 * 2 * D_INNER], acc);
        acc = fmaf(w.y, xp[-2 * 2 * D_INNER], acc);
        acc = fmaf(w.z, xp[-1 * 2 * D_INNER], acc);
        acc = fmaf(w.w, xp[0], acc);
    } else {
        acc = fmaf(w.w, xp[0], acc);
        if (t >= 1) acc = fmaf(w.z, xp[-1 * 2 * D_INNER], acc);
        if (t >= 2) acc = fmaf(w.y, xp[-2 * 2 * D_INNER], acc);
    }
    const float xc = acc / (1.0f + expf(-acc));

    float sc = 0.0f;
    const float* Sr = S + (size_t)r * D_STATE;
    #pragma unroll
    for (int s = 0; s < D_STATE; ++s)
        sc = fmaf(Sr[s], Cm[s * D_INNER + i], sc);

    const float zv = xz[(size_t)r * (2 * D_INNER) + D_INNER + i];
    const float sg = 1.0f / (1.0f + expf(-zv));
    y[(size_t)r * D_INNER + i] = f2bf((xc + sc) * sg);
}

// ---------------------------------------------------------------------------
// launch
// ---------------------------------------------------------------------------
extern "C" void kernel_launch(void* const* d_in, const int* in_sizes, int n_in,
                              void* d_out, int out_size, void* d_ws, size_t ws_size,
                              hipStream_t stream) {
    const float* x      = (const float*)d_in[0];
    const float* ln_g   = (const float*)d_in[1];
    const float* ln_b   = (const float*)d_in[2];
    const float* W_in   = (const float*)d_in[3];
    const float* conv_w = (const float*)d_in[4];
    const float* conv_b = (const float*)d_in[5];
    const float* W_out  = (const float*)d_in[6];
    const float* A      = (const float*)d_in[7];
    const float* Bm     = (const float*)d_in[8];
    const float* Cm     = (const float*)d_in[9];
    float* out = (float*)d_out;

    // workspace layout (floats first, then bf16)
    float* ws = (float*)d_ws;
    float* xz = ws;                                        // 8192*4096 f32
    float* V  = xz + (size_t)NROW * 2 * D_INNER;           // 8192*16
    float* S  = V  + (size_t)NROW * D_STATE;               // 8192*16
    unsigned short* xn_bf  = (unsigned short*)(S + (size_t)NROW * D_STATE);
    unsigned short* Win_bf = xn_bf  + (size_t)NROW * D_MODEL;           // 4096*1024
    unsigned short* Wout_bf= Win_bf + (size_t)(2 * D_INNER) * D_MODEL;  // 1024*2048
    unsigned short* y_bf   = Wout_bf + (size_t)D_MODEL * D_INNER;       // 8192*2048

    // weight conversions
    cvt_bf16<<<(2 * D_INNER * D_MODEL) / (256 * 8), 256, 0, stream>>>(W_in, Win_bf);
    cvt_bf16<<<(D_MODEL * D_INNER) / (256 * 8), 256, 0, stream>>>(W_out, Wout_bf);

    // 1. LayerNorm -> bf16
    ln_kernel<<<NROW, 256, 0, stream>>>(x, ln_g, ln_b, xn_bf);

    // 2. xz = xn @ W_in^T   (M=8192, N=4096, K=1024)
    gemm_bf16<<<dim3((2 * D_INNER) / 128, NROW / 128), 256, 0, stream>>>(
        (const short*)xn_bf, (const short*)Win_bf, nullptr, xz,
        NROW, 2 * D_INNER, D_MODEL);

    // 3. V = x_part @ Bm^T
    v_kernel<<<NROW, 256, 0, stream>>>(xz, Bm, V);

    // 4. sequential scan -> S
    scan_kernel<<<1, 64, 0, stream>>>(V, A, S);

    // 5. y = (silu(conv(x_part)) + S@Cm) * sigmoid(z) -> bf16
    y_kernel<<<(NROW * D_INNER) / 256, 256, 0, stream>>>(xz, S, Cm, conv_w, conv_b, y_bf);

    // 6. out = x + y @ W_out^T  (M=8192, N=1024, K=2048)
    gemm_bf16<<<dim3(D_MODEL / 128, NROW / 128), 256, 0, stream>>>(
        (const short*)y_bf, (const short*)Wout_bf, x, out,
        NROW, D_MODEL, D_INNER);
}

// Round 3
// 341.217 us; speedup vs baseline: 4.4410x; 1.4953x over previous
//
#include <hip/hip_runtime.h>
#include <hip/hip_bf16.h>
#include <math.h>

// Problem constants
#define D_MODEL 1024
#define D_STATE 16
#define D_CONV 4
#define D_INNER 2048
#define BATCH 2
#define SEQ 4096
#define NROW (BATCH * SEQ)          // 8192 rows (b*L + t)
#define LN_EPS 1e-5f

typedef __attribute__((ext_vector_type(8))) short  bf16x8_t;   // 8 bf16 (4 VGPRs)
typedef __attribute__((ext_vector_type(4))) float  f32x4_t;    // MFMA accumulator
typedef __attribute__((ext_vector_type(8))) unsigned short u16x8_t;

// round-to-nearest-even f32 -> bf16 (no NaN handling; data is finite)
__device__ inline unsigned short f2bf(float f) {
    unsigned u = __float_as_uint(f);
    u += 0x7fffu + ((u >> 16) & 1u);
    return (unsigned short)(u >> 16);
}
__device__ inline float bf2f(unsigned short u) {
    return __uint_as_float((unsigned)u << 16);
}

#define GLL16(g, l)                                                            \
    __builtin_amdgcn_global_load_lds(                                          \
        (const __attribute__((address_space(1))) void*)(g),                    \
        (__attribute__((address_space(3))) void*)(l), 16, 0, 0)

// ---------------------------------------------------------------------------
// 0. fp32 -> bf16 conversion (8 elements / thread)
// ---------------------------------------------------------------------------
__global__ __launch_bounds__(256) void cvt_bf16(const float* __restrict__ in,
                                                unsigned short* __restrict__ out) {
    const int i = blockIdx.x * 256 + threadIdx.x;
    const float4 a = reinterpret_cast<const float4*>(in)[2 * i];
    const float4 b = reinterpret_cast<const float4*>(in)[2 * i + 1];
    u16x8_t p;
    p[0] = f2bf(a.x); p[1] = f2bf(a.y); p[2] = f2bf(a.z); p[3] = f2bf(a.w);
    p[4] = f2bf(b.x); p[5] = f2bf(b.y); p[6] = f2bf(b.z); p[7] = f2bf(b.w);
    reinterpret_cast<u16x8_t*>(out)[i] = p;
}

// ---------------------------------------------------------------------------
// 1. LayerNorm: one block per row of 1024 floats -> bf16 output
// ---------------------------------------------------------------------------
__global__ __launch_bounds__(256) void ln_kernel(const float* __restrict__ x,
                                                 const float* __restrict__ gamma,
                                                 const float* __restrict__ beta,
                                                 unsigned short* __restrict__ xn) {
    const int row = blockIdx.x;
    const int tid = threadIdx.x;
    const float4* xr = reinterpret_cast<const float4*>(x + (size_t)row * D_MODEL);
    float4 v = xr[tid];

    __shared__ float red[8];
    const int lane = tid & 63, wave = tid >> 6;

    float s = v.x + v.y + v.z + v.w;
    #pragma unroll
    for (int off = 32; off > 0; off >>= 1) s += __shfl_down(s, off, 64);
    if (lane == 0) red[wave] = s;
    __syncthreads();
    float mu = (red[0] + red[1] + red[2] + red[3]) * (1.0f / D_MODEL);
    __syncthreads();

    float dx = v.x - mu, dy = v.y - mu, dz = v.z - mu, dw = v.w - mu;
    float ss = dx * dx + dy * dy + dz * dz + dw * dw;
    #pragma unroll
    for (int off = 32; off > 0; off >>= 1) ss += __shfl_down(ss, off, 64);
    if (lane == 0) red[wave] = ss;
    __syncthreads();
    float var = (red[0] + red[1] + red[2] + red[3]) * (1.0f / D_MODEL);
    float rs = rsqrtf(var + LN_EPS);

    const float4 gv = reinterpret_cast<const float4*>(gamma)[tid];
    const float4 bv = reinterpret_cast<const float4*>(beta)[tid];
    ushort4 o;
    o.x = f2bf(dx * rs * gv.x + bv.x);
    o.y = f2bf(dy * rs * gv.y + bv.y);
    o.z = f2bf(dz * rs * gv.z + bv.z);
    o.w = f2bf(dw * rs * gv.w + bv.w);
    reinterpret_cast<ushort4*>(xn + (size_t)row * D_MODEL)[tid] = o;
}

// ---------------------------------------------------------------------------
// 2. bf16 MFMA GEMM (TN): C = A[M,K] * B[N,K]^T. Output: bf16 (Cb) or f32+add.
//    m97 structure: 128x128 tile, BK=32, 4 waves, global_load_lds w=16.
// ---------------------------------------------------------------------------
__global__ __launch_bounds__(256) void gemm_bf16(const short* __restrict__ A,
                                                 const short* __restrict__ B,
                                                 const float* __restrict__ add,
                                                 float* __restrict__ Cf,
                                                 unsigned short* __restrict__ Cb,
                                                 int M, int N, int K) {
    __shared__ short As[128 * 32];
    __shared__ short Bs[128 * 32];

    const int tid = threadIdx.x;
    const int w = tid >> 6;
    const int l = tid & 63;
    const int row0 = blockIdx.y * 128;
    const int col0 = blockIdx.x * 128;
    const int wr = (w >> 1) * 64;
    const int wc = (w & 1) * 64;

    f32x4_t acc[4][4] = {};

    const int srow = w * 32 + (l >> 2);
    const int scol = (l & 3) * 8;
    const short* aSrc = A + (size_t)(row0 + srow) * K + scol;
    const short* bSrc = B + (size_t)(col0 + srow) * K + scol;
    const size_t rstep = (size_t)16 * K;

    const int fr = l & 15;
    const int fk = (l >> 4) * 8;

    for (int k0 = 0; k0 < K; k0 += 32) {
        GLL16(aSrc + k0,         &As[(w * 32) * 32]);
        GLL16(aSrc + k0 + rstep, &As[(w * 32 + 16) * 32]);
        GLL16(bSrc + k0,         &Bs[(w * 32) * 32]);
        GLL16(bSrc + k0 + rstep, &Bs[(w * 32 + 16) * 32]);
        __syncthreads();

        bf16x8_t af[4], bfr[4];
        #pragma unroll
        for (int m = 0; m < 4; ++m)
            af[m] = *reinterpret_cast<const bf16x8_t*>(&As[(wr + m * 16 + fr) * 32 + fk]);
        #pragma unroll
        for (int n = 0; n < 4; ++n)
            bfr[n] = *reinterpret_cast<const bf16x8_t*>(&Bs[(wc + n * 16 + fr) * 32 + fk]);

        #pragma unroll
        for (int m = 0; m < 4; ++m)
            #pragma unroll
            for (int n = 0; n < 4; ++n)
                acc[m][n] = __builtin_amdgcn_mfma_f32_16x16x32_bf16(
                    af[m], bfr[n], acc[m][n], 0, 0, 0);
        __syncthreads();
    }

    // epilogue: C/D layout col=lane&15, row=(lane>>4)*4+j
    const int cr = (l >> 4) * 4;
    const int cc = l & 15;
    #pragma unroll
    for (int m = 0; m < 4; ++m) {
        #pragma unroll
        for (int n = 0; n < 4; ++n) {
            size_t base = (size_t)(row0 + wr + m * 16 + cr) * N + (col0 + wc + n * 16 + cc);
            #pragma unroll
            for (int j = 0; j < 4; ++j) {
                float v = acc[m][n][j];
                if (Cb) {
                    Cb[base + (size_t)j * N] = f2bf(v);
                } else {
                    if (add) v += add[base + (size_t)j * N];
                    Cf[base + (size_t)j * N] = v;
                }
            }
        }
    }
}

// ---------------------------------------------------------------------------
// 3. V[r, s] = sum_i x_part[r, i] * Bm[s, i]   (x_part = xz bf16 cols 0..2047)
// ---------------------------------------------------------------------------
__global__ __launch_bounds__(256) void v_kernel(const unsigned short* __restrict__ xz,
                                                const float* __restrict__ Bm,
                                                float* __restrict__ V) {
    const int r = blockIdx.x;
    const int tid = threadIdx.x;
    const unsigned short* u = xz + (size_t)r * (2 * D_INNER);

    float acc[D_STATE];
    #pragma unroll
    for (int s = 0; s < D_STATE; ++s) acc[s] = 0.0f;

    for (int i = tid; i < D_INNER; i += 256) {
        float uv = bf2f(u[i]);
        #pragma unroll
        for (int s = 0; s < D_STATE; ++s)
            acc[s] = fmaf(uv, Bm[s * D_INNER + i], acc[s]);
    }

    #pragma unroll
    for (int s = 0; s < D_STATE; ++s)
        #pragma unroll
        for (int off = 32; off > 0; off >>= 1)
            acc[s] += __shfl_down(acc[s], off, 64);

    __shared__ float red[4][D_STATE];
    const int lane = tid & 63, wave = tid >> 6;
    if (lane == 0) {
        #pragma unroll
        for (int s = 0; s < D_STATE; ++s) red[wave][s] = acc[s];
    }
    __syncthreads();
    if (tid < D_STATE) {
        float v = red[0][tid] + red[1][tid] + red[2][tid] + red[3][tid];
        V[(size_t)r * D_STATE + tid] = v;
    }
}

// ---------------------------------------------------------------------------
// 4a. check_a: flag = (A != I) ? 1 : 0
// ---------------------------------------------------------------------------
__global__ __launch_bounds__(256) void check_a(const float* __restrict__ A,
                                               int* __restrict__ flag) {
    const int i = threadIdx.x;                      // 256 = D_STATE*D_STATE
    if (i == 0) *flag = 0;
    __syncthreads();
    const float ex = ((i >> 4) == (i & 15)) ? 1.0f : 0.0f;
    unsigned long long bad = __ballot(A[i] != ex);
    if ((i & 63) == 0 && bad) atomicOr(flag, 1);
}

// ---------------------------------------------------------------------------
// 4b. Parallel inclusive cumsum over t (A == I path).
//     One block per (b,s); thread owns 16 consecutive t's; block scan of totals.
// ---------------------------------------------------------------------------
__global__ __launch_bounds__(256) void scan_par(const float* __restrict__ V,
                                                float* __restrict__ S,
                                                const int* __restrict__ flag) {
    if (*flag) return;
    const int p = blockIdx.x;        // 0..31
    const int b = p >> 4, s = p & 15;
    const int tid = threadIdx.x;
    const float* vb = V + (size_t)b * SEQ * D_STATE + s;
    float* sb = S + (size_t)b * SEQ * D_STATE + s;

    const int t0 = tid * 16;
    float v[16];
    float run = 0.0f;
    #pragma unroll
    for (int j = 0; j < 16; ++j) {
        run += vb[(size_t)(t0 + j) * D_STATE];
        v[j] = run;
    }

    // block-wide exclusive scan of per-thread totals
    const float tot = run;
    float sc = tot;
    #pragma unroll
    for (int off = 1; off < 64; off <<= 1) {
        float n = __shfl_up(sc, off, 64);
        if ((tid & 63) >= off) sc += n;
    }
    __shared__ float wtot[4];
    if ((tid & 63) == 63) wtot[tid >> 6] = sc;
    __syncthreads();
    float woff = 0.0f;
    #pragma unroll
    for (int w2 = 0; w2 < 4; ++w2)
        if (w2 < (tid >> 6)) woff += wtot[w2];
    const float excl = sc - tot + woff;

    #pragma unroll
    for (int j = 0; j < 16; ++j)
        sb[(size_t)(t0 + j) * D_STATE] = v[j] + excl;
}

// ---------------------------------------------------------------------------
// 4c. Sequential general-A scan (fallback; no-op when A == I)
// ---------------------------------------------------------------------------
#define SCAN_CHUNK 256

__global__ __launch_bounds__(64) void scan_seq(const float* __restrict__ V,
                                               const float* __restrict__ A,
                                               float* __restrict__ S,
                                               const int* __restrict__ flag) {
    if (*flag == 0) return;
    __shared__ float Al[D_STATE * D_STATE];
    __shared__ float Vl[2 * SCAN_CHUNK * D_STATE];
    __shared__ float Sl[2 * SCAN_CHUNK * D_STATE];

    const int tid = threadIdx.x;
    for (int i = tid; i < D_STATE * D_STATE; i += 64) Al[i] = A[i];
    __syncthreads();

    float st = 0.0f;
    const int bb = (tid >> 4) & 1;
    const int ss = tid & 15;

    for (int t0 = 0; t0 < SEQ; t0 += SCAN_CHUNK) {
        for (int idx = tid; idx < 2 * SCAN_CHUNK * D_STATE; idx += 64) {
            int b = idx >> 12;
            int rem = idx & 4095;
            Vl[idx] = V[((size_t)(b * SEQ + t0) * D_STATE) + rem];
        }
        __syncthreads();

        if (tid < 32) {
            float* vb = Vl + bb * SCAN_CHUNK * D_STATE + ss;
            float* sb = Sl + bb * SCAN_CHUNK * D_STATE + ss;
            for (int t = 0; t < SCAN_CHUNK; ++t) {
                float ns = vb[t * D_STATE];
                #pragma unroll
                for (int s2 = 0; s2 < D_STATE; ++s2) {
                    float other = __shfl(st, (tid & 16) | s2, 64);
                    ns = fmaf(Al[ss * D_STATE + s2], other, ns);
                }
                st = ns;
                sb[t * D_STATE] = st;
            }
        }
        __syncthreads();

        for (int idx = tid; idx < 2 * SCAN_CHUNK * D_STATE; idx += 64) {
            int b = idx >> 12;
            int rem = idx & 4095;
            S[((size_t)(b * SEQ + t0) * D_STATE) + rem] = Sl[idx];
        }
        __syncthreads();
    }
}

// ---------------------------------------------------------------------------
// 5. y = (silu(conv(x_part)) + S @ Cm) * sigmoid(z)  -> bf16 output
// ---------------------------------------------------------------------------
__global__ __launch_bounds__(256) void y_kernel(const unsigned short* __restrict__ xz,
                                                const float* __restrict__ S,
                                                const float* __restrict__ Cm,
                                                const float* __restrict__ convw,
                                                const float* __restrict__ convb,
                                                unsigned short* __restrict__ y) {
    const int gid = blockIdx.x * 256 + threadIdx.x;
    const int r = gid >> 11;
    const int i = gid & (D_INNER - 1);
    const int t = r & (SEQ - 1);

    const float4 w = *reinterpret_cast<const float4*>(&convw[i * D_CONV]);
    const unsigned short* xp = xz + (size_t)r * (2 * D_INNER) + i;

    float acc = convb[i];
    if (t >= 3) {
        acc = fmaf(w.x, bf2f(xp[-3 * 2 * D_INNER]), acc);
        acc = fmaf(w.y, bf2f(xp[-2 * 2 * D_INNER]), acc);
        acc = fmaf(w.z, bf2f(xp[-1 * 2 * D_INNER]), acc);
        acc = fmaf(w.w, bf2f(xp[0]), acc);
    } else {
        acc = fmaf(w.w, bf2f(xp[0]), acc);
        if (t >= 1) acc = fmaf(w.z, bf2f(xp[-1 * 2 * D_INNER]), acc);
        if (t >= 2) acc = fmaf(w.y, bf2f(xp[-2 * 2 * D_INNER]), acc);
    }
    const float xc = acc / (1.0f + expf(-acc));

    float sc = 0.0f;
    const float* Sr = S + (size_t)r * D_STATE;
    #pragma unroll
    for (int s = 0; s < D_STATE; ++s)
        sc = fmaf(Sr[s], Cm[s * D_INNER + i], sc);

    const float zv = bf2f(xz[(size_t)r * (2 * D_INNER) + D_INNER + i]);
    const float sg = 1.0f / (1.0f + expf(-zv));
    y[(size_t)r * D_INNER + i] = f2bf((xc + sc) * sg);
}

// ---------------------------------------------------------------------------
// launch
// ---------------------------------------------------------------------------
extern "C" void kernel_launch(void* const* d_in, const int* in_sizes, int n_in,
                              void* d_out, int out_size, void* d_ws, size_t ws_size,
                              hipStream_t stream) {
    const float* x      = (const float*)d_in[0];
    const float* ln_g   = (const float*)d_in[1];
    const float* ln_b   = (const float*)d_in[2];
    const float* W_in   = (const float*)d_in[3];
    const float* conv_w = (const float*)d_in[4];
    const float* conv_b = (const float*)d_in[5];
    const float* W_out  = (const float*)d_in[6];
    const float* A      = (const float*)d_in[7];
    const float* Bm     = (const float*)d_in[8];
    const float* Cm     = (const float*)d_in[9];
    float* out = (float*)d_out;

    // workspace layout
    float* ws = (float*)d_ws;
    float* V  = ws;                                        // 8192*16 f32
    float* S  = V + (size_t)NROW * D_STATE;                // 8192*16 f32
    int*   flag = (int*)(S + (size_t)NROW * D_STATE);
    unsigned short* xz_bf  = (unsigned short*)(flag + 64); // 8192*4096 bf16
    unsigned short* xn_bf  = xz_bf  + (size_t)NROW * 2 * D_INNER;
    unsigned short* Win_bf = xn_bf  + (size_t)NROW * D_MODEL;
    unsigned short* Wout_bf= Win_bf + (size_t)(2 * D_INNER) * D_MODEL;
    unsigned short* y_bf   = Wout_bf + (size_t)D_MODEL * D_INNER;

    // weight conversions
    cvt_bf16<<<(2 * D_INNER * D_MODEL) / (256 * 8), 256, 0, stream>>>(W_in, Win_bf);
    cvt_bf16<<<(D_MODEL * D_INNER) / (256 * 8), 256, 0, stream>>>(W_out, Wout_bf);

    // 1. LayerNorm -> bf16
    ln_kernel<<<NROW, 256, 0, stream>>>(x, ln_g, ln_b, xn_bf);

    // 2. xz = xn @ W_in^T -> bf16   (M=8192, N=4096, K=1024)
    gemm_bf16<<<dim3((2 * D_INNER) / 128, NROW / 128), 256, 0, stream>>>(
        (const short*)xn_bf, (const short*)Win_bf, nullptr, nullptr, xz_bf,
        NROW, 2 * D_INNER, D_MODEL);

    // 3. V = x_part @ Bm^T
    v_kernel<<<NROW, 256, 0, stream>>>(xz_bf, Bm, V);

    // 4. scan: parallel cumsum when A==I, sequential general fallback otherwise
    check_a<<<1, 256, 0, stream>>>(A, flag);
    scan_par<<<32, 256, 0, stream>>>(V, S, flag);
    scan_seq<<<1, 64, 0, stream>>>(V, A, S, flag);

    // 5. y = (silu(conv(x_part)) + S@Cm) * sigmoid(z) -> bf16
    y_kernel<<<(NROW * D_INNER) / 256, 256, 0, stream>>>(xz_bf, S, Cm, conv_w, conv_b, y_bf);

    // 6. out = x + y @ W_out^T  (M=8192, N=1024, K=2048)
    gemm_bf16<<<dim3(D_MODEL / 128, NROW / 128), 256, 0, stream>>>(
        (const short*)y_bf, (const short*)Wout_bf, x, out, nullptr,
        NROW, D_MODEL, D_INNER);
}

// Round 4
// 261.865 us; speedup vs baseline: 5.7868x; 1.3030x over previous
//
#include <hip/hip_runtime.h>
#include <hip/hip_bf16.h>
#include <math.h>

// Problem constants
#define D_MODEL 1024
#define D_STATE 16
#define D_CONV 4
#define D_INNER 2048
#define BATCH 2
#define SEQ 4096
#define NROW (BATCH * SEQ)          // 8192 rows (b*L + t)
#define LN_EPS 1e-5f

typedef __attribute__((ext_vector_type(8))) short  bf16x8_t;   // 8 bf16 (4 VGPRs)
typedef __attribute__((ext_vector_type(4))) float  f32x4_t;    // MFMA accumulator
typedef __attribute__((ext_vector_type(8))) unsigned short u16x8_t;

// round-to-nearest-even f32 -> bf16 (no NaN handling; data is finite)
__device__ inline unsigned short f2bf(float f) {
    unsigned u = __float_as_uint(f);
    u += 0x7fffu + ((u >> 16) & 1u);
    return (unsigned short)(u >> 16);
}
__device__ inline float bf2f(unsigned short u) {
    return __uint_as_float((unsigned)u << 16);
}

#define GLL16(g, l)                                                            \
    __builtin_amdgcn_global_load_lds(                                          \
        (const __attribute__((address_space(1))) void*)(g),                    \
        (__attribute__((address_space(3))) void*)(l), 16, 0, 0)

// ---------------------------------------------------------------------------
// 0. fp32 -> bf16 conversion (8 elements / thread)
// ---------------------------------------------------------------------------
__global__ __launch_bounds__(256) void cvt_bf16(const float* __restrict__ in,
                                                unsigned short* __restrict__ out) {
    const int i = blockIdx.x * 256 + threadIdx.x;
    const float4 a = reinterpret_cast<const float4*>(in)[2 * i];
    const float4 b = reinterpret_cast<const float4*>(in)[2 * i + 1];
    u16x8_t p;
    p[0] = f2bf(a.x); p[1] = f2bf(a.y); p[2] = f2bf(a.z); p[3] = f2bf(a.w);
    p[4] = f2bf(b.x); p[5] = f2bf(b.y); p[6] = f2bf(b.z); p[7] = f2bf(b.w);
    reinterpret_cast<u16x8_t*>(out)[i] = p;
}

// ---------------------------------------------------------------------------
// 1. LayerNorm: one block per row of 1024 floats -> bf16 output
// ---------------------------------------------------------------------------
__global__ __launch_bounds__(256) void ln_kernel(const float* __restrict__ x,
                                                 const float* __restrict__ gamma,
                                                 const float* __restrict__ beta,
                                                 unsigned short* __restrict__ xn) {
    const int row = blockIdx.x;
    const int tid = threadIdx.x;
    const float4* xr = reinterpret_cast<const float4*>(x + (size_t)row * D_MODEL);
    float4 v = xr[tid];

    __shared__ float red[8];
    const int lane = tid & 63, wave = tid >> 6;

    float s = v.x + v.y + v.z + v.w;
    #pragma unroll
    for (int off = 32; off > 0; off >>= 1) s += __shfl_down(s, off, 64);
    if (lane == 0) red[wave] = s;
    __syncthreads();
    float mu = (red[0] + red[1] + red[2] + red[3]) * (1.0f / D_MODEL);
    __syncthreads();

    float dx = v.x - mu, dy = v.y - mu, dz = v.z - mu, dw = v.w - mu;
    float ss = dx * dx + dy * dy + dz * dz + dw * dw;
    #pragma unroll
    for (int off = 32; off > 0; off >>= 1) ss += __shfl_down(ss, off, 64);
    if (lane == 0) red[wave] = ss;
    __syncthreads();
    float var = (red[0] + red[1] + red[2] + red[3]) * (1.0f / D_MODEL);
    float rs = rsqrtf(var + LN_EPS);

    const float4 gv = reinterpret_cast<const float4*>(gamma)[tid];
    const float4 bv = reinterpret_cast<const float4*>(beta)[tid];
    ushort4 o;
    o.x = f2bf(dx * rs * gv.x + bv.x);
    o.y = f2bf(dy * rs * gv.y + bv.y);
    o.z = f2bf(dz * rs * gv.z + bv.z);
    o.w = f2bf(dw * rs * gv.w + bv.w);
    reinterpret_cast<ushort4*>(xn + (size_t)row * D_MODEL)[tid] = o;
}

// ---------------------------------------------------------------------------
// 2. bf16 MFMA GEMM (TN): C = A[M,K] * B[N,K]^T. Output: bf16 (Cb) or f32+add.
//    m97 structure: 128x128 tile, BK=32, 4 waves, global_load_lds w=16.
// ---------------------------------------------------------------------------
__global__ __launch_bounds__(256) void gemm_bf16(const short* __restrict__ A,
                                                 const short* __restrict__ B,
                                                 const float* __restrict__ add,
                                                 float* __restrict__ Cf,
                                                 unsigned short* __restrict__ Cb,
                                                 int M, int N, int K) {
    __shared__ short As[128 * 32];
    __shared__ short Bs[128 * 32];

    const int tid = threadIdx.x;
    const int w = tid >> 6;
    const int l = tid & 63;
    const int row0 = blockIdx.y * 128;
    const int col0 = blockIdx.x * 128;
    const int wr = (w >> 1) * 64;
    const int wc = (w & 1) * 64;

    f32x4_t acc[4][4] = {};

    const int srow = w * 32 + (l >> 2);
    const int scol = (l & 3) * 8;
    const short* aSrc = A + (size_t)(row0 + srow) * K + scol;
    const short* bSrc = B + (size_t)(col0 + srow) * K + scol;
    const size_t rstep = (size_t)16 * K;

    const int fr = l & 15;
    const int fk = (l >> 4) * 8;

    for (int k0 = 0; k0 < K; k0 += 32) {
        GLL16(aSrc + k0,         &As[(w * 32) * 32]);
        GLL16(aSrc + k0 + rstep, &As[(w * 32 + 16) * 32]);
        GLL16(bSrc + k0,         &Bs[(w * 32) * 32]);
        GLL16(bSrc + k0 + rstep, &Bs[(w * 32 + 16) * 32]);
        __syncthreads();

        bf16x8_t af[4], bfr[4];
        #pragma unroll
        for (int m = 0; m < 4; ++m)
            af[m] = *reinterpret_cast<const bf16x8_t*>(&As[(wr + m * 16 + fr) * 32 + fk]);
        #pragma unroll
        for (int n = 0; n < 4; ++n)
            bfr[n] = *reinterpret_cast<const bf16x8_t*>(&Bs[(wc + n * 16 + fr) * 32 + fk]);

        #pragma unroll
        for (int m = 0; m < 4; ++m)
            #pragma unroll
            for (int n = 0; n < 4; ++n)
                acc[m][n] = __builtin_amdgcn_mfma_f32_16x16x32_bf16(
                    af[m], bfr[n], acc[m][n], 0, 0, 0);
        __syncthreads();
    }

    // epilogue: C/D layout col=lane&15, row=(lane>>4)*4+j
    const int cr = (l >> 4) * 4;
    const int cc = l & 15;
    #pragma unroll
    for (int m = 0; m < 4; ++m) {
        #pragma unroll
        for (int n = 0; n < 4; ++n) {
            size_t base = (size_t)(row0 + wr + m * 16 + cr) * N + (col0 + wc + n * 16 + cc);
            #pragma unroll
            for (int j = 0; j < 4; ++j) {
                float v = acc[m][n][j];
                if (Cb) {
                    Cb[base + (size_t)j * N] = f2bf(v);
                } else {
                    if (add) v += add[base + (size_t)j * N];
                    Cf[base + (size_t)j * N] = v;
                }
            }
        }
    }
}

// ---------------------------------------------------------------------------
// 3. V = x_part @ Bm^T via MFMA. One wave per 16 rows, K=2048, direct global
//    fragment loads (Bm pre-converted to bf16, L2-resident).
// ---------------------------------------------------------------------------
__global__ __launch_bounds__(64) void v_mfma(const unsigned short* __restrict__ xz,
                                             const unsigned short* __restrict__ Bmb,
                                             float* __restrict__ V) {
    const int l = threadIdx.x;
    const int r0 = blockIdx.x * 16;
    const int fr = l & 15;
    const int fk = (l >> 4) * 8;

    const unsigned short* aP = xz + (size_t)(r0 + fr) * (2 * D_INNER) + fk;
    const unsigned short* bP = Bmb + fr * D_INNER + fk;

    f32x4_t acc = {};
    #pragma unroll 4
    for (int k0 = 0; k0 < D_INNER; k0 += 32) {
        bf16x8_t a = *reinterpret_cast<const bf16x8_t*>(aP + k0);
        bf16x8_t b = *reinterpret_cast<const bf16x8_t*>(bP + k0);
        acc = __builtin_amdgcn_mfma_f32_16x16x32_bf16(a, b, acc, 0, 0, 0);
    }

    const int cr = (l >> 4) * 4;
    const int cc = l & 15;
    #pragma unroll
    for (int j = 0; j < 4; ++j)
        V[(size_t)(r0 + cr + j) * D_STATE + cc] = acc[j];
}

// ---------------------------------------------------------------------------
// 4a. check_a: flag = (A != I) ? 1 : 0
// ---------------------------------------------------------------------------
__global__ __launch_bounds__(256) void check_a(const float* __restrict__ A,
                                               int* __restrict__ flag) {
    const int i = threadIdx.x;
    if (i == 0) *flag = 0;
    __syncthreads();
    const float ex = ((i >> 4) == (i & 15)) ? 1.0f : 0.0f;
    unsigned long long bad = __ballot(A[i] != ex);
    if ((i & 63) == 0 && bad) atomicOr(flag, 1);
}

// ---------------------------------------------------------------------------
// 4b. Parallel inclusive cumsum over t (A == I path).
// ---------------------------------------------------------------------------
__global__ __launch_bounds__(256) void scan_par(const float* __restrict__ V,
                                                float* __restrict__ S,
                                                const int* __restrict__ flag) {
    if (*flag) return;
    const int p = blockIdx.x;        // 0..31
    const int b = p >> 4, s = p & 15;
    const int tid = threadIdx.x;
    const float* vb = V + (size_t)b * SEQ * D_STATE + s;
    float* sb = S + (size_t)b * SEQ * D_STATE + s;

    const int t0 = tid * 16;
    float v[16];
    float run = 0.0f;
    #pragma unroll
    for (int j = 0; j < 16; ++j) {
        run += vb[(size_t)(t0 + j) * D_STATE];
        v[j] = run;
    }

    const float tot = run;
    float sc = tot;
    #pragma unroll
    for (int off = 1; off < 64; off <<= 1) {
        float n = __shfl_up(sc, off, 64);
        if ((tid & 63) >= off) sc += n;
    }
    __shared__ float wtot[4];
    if ((tid & 63) == 63) wtot[tid >> 6] = sc;
    __syncthreads();
    float woff = 0.0f;
    #pragma unroll
    for (int w2 = 0; w2 < 4; ++w2)
        if (w2 < (tid >> 6)) woff += wtot[w2];
    const float excl = sc - tot + woff;

    #pragma unroll
    for (int j = 0; j < 16; ++j)
        sb[(size_t)(t0 + j) * D_STATE] = v[j] + excl;
}

// ---------------------------------------------------------------------------
// 4c. Sequential general-A scan (fallback; no-op when A == I)
// ---------------------------------------------------------------------------
#define SCAN_CHUNK 256

__global__ __launch_bounds__(64) void scan_seq(const float* __restrict__ V,
                                               const float* __restrict__ A,
                                               float* __restrict__ S,
                                               const int* __restrict__ flag) {
    if (*flag == 0) return;
    __shared__ float Al[D_STATE * D_STATE];
    __shared__ float Vl[2 * SCAN_CHUNK * D_STATE];
    __shared__ float Sl[2 * SCAN_CHUNK * D_STATE];

    const int tid = threadIdx.x;
    for (int i = tid; i < D_STATE * D_STATE; i += 64) Al[i] = A[i];
    __syncthreads();

    float st = 0.0f;
    const int bb = (tid >> 4) & 1;
    const int ss = tid & 15;

    for (int t0 = 0; t0 < SEQ; t0 += SCAN_CHUNK) {
        for (int idx = tid; idx < 2 * SCAN_CHUNK * D_STATE; idx += 64) {
            int b = idx >> 12;
            int rem = idx & 4095;
            Vl[idx] = V[((size_t)(b * SEQ + t0) * D_STATE) + rem];
        }
        __syncthreads();

        if (tid < 32) {
            float* vb = Vl + bb * SCAN_CHUNK * D_STATE + ss;
            float* sb = Sl + bb * SCAN_CHUNK * D_STATE + ss;
            for (int t = 0; t < SCAN_CHUNK; ++t) {
                float ns = vb[t * D_STATE];
                #pragma unroll
                for (int s2 = 0; s2 < D_STATE; ++s2) {
                    float other = __shfl(st, (tid & 16) | s2, 64);
                    ns = fmaf(Al[ss * D_STATE + s2], other, ns);
                }
                st = ns;
                sb[t * D_STATE] = st;
            }
        }
        __syncthreads();

        for (int idx = tid; idx < 2 * SCAN_CHUNK * D_STATE; idx += 64) {
            int b = idx >> 12;
            int rem = idx & 4095;
            S[((size_t)(b * SEQ + t0) * D_STATE) + rem] = Sl[idx];
        }
        __syncthreads();
    }
}

// ---------------------------------------------------------------------------
// 5. y = (silu(conv(x_part)) + S @ Cm) * sigmoid(z)  -> bf16 output
//    Block = 512-wide i-tile x 64 rows. Per thread: 2 fixed columns.
//    Cm columns in registers (loaded once); conv taps in rolling window.
// ---------------------------------------------------------------------------
__global__ __launch_bounds__(256) void y_kernel(const unsigned short* __restrict__ xz,
                                                const float* __restrict__ S,
                                                const float* __restrict__ Cm,
                                                const float* __restrict__ convw,
                                                const float* __restrict__ convb,
                                                unsigned short* __restrict__ y) {
    const int tid = threadIdx.x;
    const int i0 = blockIdx.x * 512 + tid * 2;
    const int r0 = blockIdx.y * 64;
    const int tb0 = r0 & (SEQ - 1);          // t of first row (chunks never straddle batch)

    // per-column constants
    const float4 w0 = *reinterpret_cast<const float4*>(&convw[i0 * D_CONV]);
    const float4 w1 = *reinterpret_cast<const float4*>(&convw[(i0 + 1) * D_CONV]);
    const float cb0 = convb[i0], cb1 = convb[i0 + 1];
    float cm0[D_STATE], cm1[D_STATE];
    #pragma unroll
    for (int s = 0; s < D_STATE; ++s) {
        float2 c = *reinterpret_cast<const float2*>(&Cm[s * D_INNER + i0]);
        cm0[s] = c.x; cm1[s] = c.y;
    }

    // rolling causal window (rows r-1, r-2, r-3), zero-padded at batch start
    float2 xm1 = make_float2(0.f, 0.f), xm2 = xm1, xm3 = xm1;
    if (tb0 >= 1) { ushort2 u = *reinterpret_cast<const ushort2*>(&xz[(size_t)(r0 - 1) * (2 * D_INNER) + i0]); xm1 = make_float2(bf2f(u.x), bf2f(u.y)); }
    if (tb0 >= 2) { ushort2 u = *reinterpret_cast<const ushort2*>(&xz[(size_t)(r0 - 2) * (2 * D_INNER) + i0]); xm2 = make_float2(bf2f(u.x), bf2f(u.y)); }
    if (tb0 >= 3) { ushort2 u = *reinterpret_cast<const ushort2*>(&xz[(size_t)(r0 - 3) * (2 * D_INNER) + i0]); xm3 = make_float2(bf2f(u.x), bf2f(u.y)); }

    for (int r = r0; r < r0 + 64; ++r) {
        const ushort2 xu = *reinterpret_cast<const ushort2*>(&xz[(size_t)r * (2 * D_INNER) + i0]);
        const ushort2 zu = *reinterpret_cast<const ushort2*>(&xz[(size_t)r * (2 * D_INNER) + D_INNER + i0]);
        const float2 x0 = make_float2(bf2f(xu.x), bf2f(xu.y));

        float a0 = cb0;
        a0 = fmaf(w0.x, xm3.x, a0); a0 = fmaf(w0.y, xm2.x, a0);
        a0 = fmaf(w0.z, xm1.x, a0); a0 = fmaf(w0.w, x0.x, a0);
        float a1 = cb1;
        a1 = fmaf(w1.x, xm3.y, a1); a1 = fmaf(w1.y, xm2.y, a1);
        a1 = fmaf(w1.z, xm1.y, a1); a1 = fmaf(w1.w, x0.y, a1);

        const float xc0 = a0 / (1.0f + expf(-a0));
        const float xc1 = a1 / (1.0f + expf(-a1));

        const float4* Sp = reinterpret_cast<const float4*>(S + (size_t)r * D_STATE);
        const float4 s0 = Sp[0], s1 = Sp[1], s2 = Sp[2], s3 = Sp[3];
        const float sv[D_STATE] = {s0.x, s0.y, s0.z, s0.w, s1.x, s1.y, s1.z, s1.w,
                                   s2.x, s2.y, s2.z, s2.w, s3.x, s3.y, s3.z, s3.w};
        float sc0 = 0.f, sc1 = 0.f;
        #pragma unroll
        for (int s = 0; s < D_STATE; ++s) {
            sc0 = fmaf(sv[s], cm0[s], sc0);
            sc1 = fmaf(sv[s], cm1[s], sc1);
        }

        const float z0 = bf2f(zu.x), z1 = bf2f(zu.y);
        const float g0 = 1.0f / (1.0f + expf(-z0));
        const float g1 = 1.0f / (1.0f + expf(-z1));

        ushort2 o;
        o.x = f2bf((xc0 + sc0) * g0);
        o.y = f2bf((xc1 + sc1) * g1);
        *reinterpret_cast<ushort2*>(&y[(size_t)r * D_INNER + i0]) = o;

        xm3 = xm2; xm2 = xm1; xm1 = x0;
    }
}

// ---------------------------------------------------------------------------
// launch
// ---------------------------------------------------------------------------
extern "C" void kernel_launch(void* const* d_in, const int* in_sizes, int n_in,
                              void* d_out, int out_size, void* d_ws, size_t ws_size,
                              hipStream_t stream) {
    const float* x      = (const float*)d_in[0];
    const float* ln_g   = (const float*)d_in[1];
    const float* ln_b   = (const float*)d_in[2];
    const float* W_in   = (const float*)d_in[3];
    const float* conv_w = (const float*)d_in[4];
    const float* conv_b = (const float*)d_in[5];
    const float* W_out  = (const float*)d_in[6];
    const float* A      = (const float*)d_in[7];
    const float* Bm     = (const float*)d_in[8];
    const float* Cm     = (const float*)d_in[9];
    float* out = (float*)d_out;

    // workspace layout
    float* ws = (float*)d_ws;
    float* V  = ws;                                        // 8192*16 f32
    float* S  = V + (size_t)NROW * D_STATE;                // 8192*16 f32
    int*   flag = (int*)(S + (size_t)NROW * D_STATE);
    unsigned short* xz_bf  = (unsigned short*)(flag + 64); // 8192*4096 bf16
    unsigned short* xn_bf  = xz_bf  + (size_t)NROW * 2 * D_INNER;
    unsigned short* Win_bf = xn_bf  + (size_t)NROW * D_MODEL;
    unsigned short* Wout_bf= Win_bf + (size_t)(2 * D_INNER) * D_MODEL;
    unsigned short* y_bf   = Wout_bf + (size_t)D_MODEL * D_INNER;
    unsigned short* Bm_bf  = y_bf   + (size_t)NROW * D_INNER;

    // weight conversions
    cvt_bf16<<<(2 * D_INNER * D_MODEL) / (256 * 8), 256, 0, stream>>>(W_in, Win_bf);
    cvt_bf16<<<(D_MODEL * D_INNER) / (256 * 8), 256, 0, stream>>>(W_out, Wout_bf);
    cvt_bf16<<<(D_STATE * D_INNER) / (256 * 8), 256, 0, stream>>>(Bm, Bm_bf);

    // 1. LayerNorm -> bf16
    ln_kernel<<<NROW, 256, 0, stream>>>(x, ln_g, ln_b, xn_bf);

    // 2. xz = xn @ W_in^T -> bf16   (M=8192, N=4096, K=1024)
    gemm_bf16<<<dim3((2 * D_INNER) / 128, NROW / 128), 256, 0, stream>>>(
        (const short*)xn_bf, (const short*)Win_bf, nullptr, nullptr, xz_bf,
        NROW, 2 * D_INNER, D_MODEL);

    // 3. V = x_part @ Bm^T  (MFMA, one wave / 16 rows)
    v_mfma<<<NROW / 16, 64, 0, stream>>>(xz_bf, Bm_bf, V);

    // 4. scan: parallel cumsum when A==I, sequential general fallback otherwise
    check_a<<<1, 256, 0, stream>>>(A, flag);
    scan_par<<<32, 256, 0, stream>>>(V, S, flag);
    scan_seq<<<1, 64, 0, stream>>>(V, A, S, flag);

    // 5. y = (silu(conv(x_part)) + S@Cm) * sigmoid(z) -> bf16
    y_kernel<<<dim3(D_INNER / 512, NROW / 64), 256, 0, stream>>>(
        xz_bf, S, Cm, conv_w, conv_b, y_bf);

    // 6. out = x + y @ W_out^T  (M=8192, N=1024, K=2048)
    gemm_bf16<<<dim3(D_MODEL / 128, NROW / 128), 256, 0, stream>>>(
        (const short*)y_bf, (const short*)Wout_bf, x, out, nullptr,
        NROW, D_MODEL, D_INNER);
}

// Round 5
// 239.977 us; speedup vs baseline: 6.3146x; 1.0912x over previous
//
#include <hip/hip_runtime.h>
#include <hip/hip_bf16.h>
#include <math.h>

// Problem constants
#define D_MODEL 1024
#define D_STATE 16
#define D_CONV 4
#define D_INNER 2048
#define BATCH 2
#define SEQ 4096
#define NROW (BATCH * SEQ)          // 8192 rows (b*L + t)
#define LN_EPS 1e-5f

typedef __attribute__((ext_vector_type(8))) short  bf16x8_t;   // 8 bf16 (4 VGPRs)
typedef __attribute__((ext_vector_type(4))) float  f32x4_t;    // MFMA accumulator
typedef __attribute__((ext_vector_type(8))) unsigned short u16x8_t;

// round-to-nearest-even f32 -> bf16 (no NaN handling; data is finite)
__device__ inline unsigned short f2bf(float f) {
    unsigned u = __float_as_uint(f);
    u += 0x7fffu + ((u >> 16) & 1u);
    return (unsigned short)(u >> 16);
}
__device__ inline float bf2f(unsigned short u) {
    return __uint_as_float((unsigned)u << 16);
}

#define GLL16(g, l)                                                            \
    __builtin_amdgcn_global_load_lds(                                          \
        (const __attribute__((address_space(1))) void*)(g),                    \
        (__attribute__((address_space(3))) void*)(l), 16, 0, 0)

#define FENCE asm volatile("" ::: "memory")
#define BAR do { FENCE; __builtin_amdgcn_s_barrier(); FENCE; } while (0)

// ---------------------------------------------------------------------------
// 0. fp32 -> bf16 conversion (8 elements / thread)
// ---------------------------------------------------------------------------
__global__ __launch_bounds__(256) void cvt_bf16(const float* __restrict__ in,
                                                unsigned short* __restrict__ out) {
    const int i = blockIdx.x * 256 + threadIdx.x;
    const float4 a = reinterpret_cast<const float4*>(in)[2 * i];
    const float4 b = reinterpret_cast<const float4*>(in)[2 * i + 1];
    u16x8_t p;
    p[0] = f2bf(a.x); p[1] = f2bf(a.y); p[2] = f2bf(a.z); p[3] = f2bf(a.w);
    p[4] = f2bf(b.x); p[5] = f2bf(b.y); p[6] = f2bf(b.z); p[7] = f2bf(b.w);
    reinterpret_cast<u16x8_t*>(out)[i] = p;
}

// ---------------------------------------------------------------------------
// 1. LayerNorm: one block per row of 1024 floats -> bf16 output
// ---------------------------------------------------------------------------
__global__ __launch_bounds__(256) void ln_kernel(const float* __restrict__ x,
                                                 const float* __restrict__ gamma,
                                                 const float* __restrict__ beta,
                                                 unsigned short* __restrict__ xn) {
    const int row = blockIdx.x;
    const int tid = threadIdx.x;
    const float4* xr = reinterpret_cast<const float4*>(x + (size_t)row * D_MODEL);
    float4 v = xr[tid];

    __shared__ float red[8];
    const int lane = tid & 63, wave = tid >> 6;

    float s = v.x + v.y + v.z + v.w;
    #pragma unroll
    for (int off = 32; off > 0; off >>= 1) s += __shfl_down(s, off, 64);
    if (lane == 0) red[wave] = s;
    __syncthreads();
    float mu = (red[0] + red[1] + red[2] + red[3]) * (1.0f / D_MODEL);
    __syncthreads();

    float dx = v.x - mu, dy = v.y - mu, dz = v.z - mu, dw = v.w - mu;
    float ss = dx * dx + dy * dy + dz * dz + dw * dw;
    #pragma unroll
    for (int off = 32; off > 0; off >>= 1) ss += __shfl_down(ss, off, 64);
    if (lane == 0) red[wave] = ss;
    __syncthreads();
    float var = (red[0] + red[1] + red[2] + red[3]) * (1.0f / D_MODEL);
    float rs = rsqrtf(var + LN_EPS);

    const float4 gv = reinterpret_cast<const float4*>(gamma)[tid];
    const float4 bv = reinterpret_cast<const float4*>(beta)[tid];
    ushort4 o;
    o.x = f2bf(dx * rs * gv.x + bv.x);
    o.y = f2bf(dy * rs * gv.y + bv.y);
    o.z = f2bf(dz * rs * gv.z + bv.z);
    o.w = f2bf(dw * rs * gv.w + bv.w);
    reinterpret_cast<ushort4*>(xn + (size_t)row * D_MODEL)[tid] = o;
}

// ---------------------------------------------------------------------------
// 2a. 256x256 8-phase bf16 MFMA GEMM (TN), bf16 output.
//     BK=64, 8 waves (2Mx4N), per-wave 128x64 output, 128 KiB LDS dbuf,
//     st_16x32 swizzle (pre-swizzled global src + swizzled ds_read),
//     counted vmcnt(6), raw s_barrier, setprio around MFMA clusters.
//     LDS map: buf(2) x quarter(4: A rows0-127, A rows128-255, B0-127, B128-255)
//              x 128x64 bf16 linear row-major.
// ---------------------------------------------------------------------------
__global__ __launch_bounds__(512) void gemm256_bf16(const short* __restrict__ A,
                                                    const short* __restrict__ B,
                                                    unsigned short* __restrict__ Cb,
                                                    int M, int N, int K) {
    __shared__ short lds[2 * 4 * 8192];   // 128 KiB

    const int tid = threadIdx.x;
    const int w = tid >> 6, l = tid & 63;
    const int row0 = blockIdx.y * 256;
    const int col0 = blockIdx.x * 256;
    const int wm = w >> 2;               // 0..1  (M wave)
    const int wn = w & 3;                // 0..3  (N wave)
    const int fr = l & 15;
    const int fc = (l >> 4) * 8;         // 0,8,16,24
    const int NT = K >> 6;               // K-tiles of 64

    const int qa = wm;                   // wave's A quarter
    const int qb = 2 + (wn >> 1);        // wave's B quarter
    const int bb = (wn & 1) * 64;        // wave's row base within B quarter

    // stage one 128x64 half-tile (quarter q of buffer buf) from G rows
    // [growbase, growbase+128) cols [k0, k0+64). Linear LDS dest, source col
    // pre-swizzled with the st_16x32 involution (c ^= 16 when r&4).
    auto STAGE = [&](const short* __restrict__ G, int growbase, int k0,
                     int buf, int q) {
        #pragma unroll
        for (int j = 0; j < 2; ++j) {
            const int e = ((j * 8 + w) << 9) + l * 8;    // element in quarter
            const int r = e >> 6;
            const int c = (e & 63) ^ ((r & 4) << 2);
            GLL16(G + (size_t)(growbase + r) * K + k0 + c,
                  &lds[buf * 32768 + q * 8192 + ((j * 8 + w) << 9)]);
        }
    };
    // read one MFMA fragment (8 bf16) at quarter-local row r, k-substep ks
    auto LDF = [&](int buf, int q, int r, int ks) -> bf16x8_t {
        int c = ks * 32 + fc;
        c ^= (r & 4) << 2;               // st_16x32 swizzle on read
        return *reinterpret_cast<const bf16x8_t*>(
            &lds[buf * 32768 + q * 8192 + r * 64 + c]);
    };

    f32x4_t acc[8][4] = {};
    bf16x8_t af[4][2], bA[2][2], bB[2][2];

#define MFMA_Q(mh, nh, bfr)                                                    \
    do {                                                                       \
        _Pragma("unroll")                                                      \
        for (int mi = 0; mi < 4; ++mi)                                         \
            _Pragma("unroll")                                                  \
            for (int ni = 0; ni < 2; ++ni)                                     \
                _Pragma("unroll")                                              \
                for (int ks = 0; ks < 2; ++ks)                                 \
                    acc[(mh) * 4 + mi][(nh) * 2 + ni] =                        \
                        __builtin_amdgcn_mfma_f32_16x16x32_bf16(               \
                            af[mi][ks], bfr[ni][ks],                           \
                            acc[(mh) * 4 + mi][(nh) * 2 + ni], 0, 0, 0);       \
    } while (0)

    // ---- prologue: k0 all 4 quarters (buf0); k1 B quarters + A-q0 (buf1)
    STAGE(A, row0,       0, 0, 0);
    STAGE(A, row0 + 128, 0, 0, 1);
    STAGE(B, col0,       0, 0, 2);
    STAGE(B, col0 + 128, 0, 0, 3);
    if (NT > 1) {
        STAGE(B, col0,       64, 1, 2);
        STAGE(B, col0 + 128, 64, 1, 3);
        STAGE(A, row0,       64, 1, 0);
        asm volatile("s_waitcnt vmcnt(6)" ::: "memory");
    } else {
        asm volatile("s_waitcnt vmcnt(0)" ::: "memory");
    }
    BAR;

    for (int kt = 0; kt < NT; ++kt) {
        const int buf = kt & 1, nbuf = buf ^ 1;
        // ---- phase 0: read a(mh0)+bA(nh0); stage A-q1 of kt+1
        #pragma unroll
        for (int mi = 0; mi < 4; ++mi)
            #pragma unroll
            for (int ks = 0; ks < 2; ++ks)
                af[mi][ks] = LDF(buf, qa, mi * 16 + fr, ks);
        #pragma unroll
        for (int ni = 0; ni < 2; ++ni)
            #pragma unroll
            for (int ks = 0; ks < 2; ++ks)
                bA[ni][ks] = LDF(buf, qb, bb + ni * 16 + fr, ks);
        if (kt + 1 < NT) STAGE(A, row0 + 128, (kt + 1) << 6, nbuf, 1);
        BAR;
        __builtin_amdgcn_s_setprio(1);
        MFMA_Q(0, 0, bA);
        __builtin_amdgcn_s_setprio(0);
        BAR;
        // ---- phase 1: read bB(nh1)
        #pragma unroll
        for (int ni = 0; ni < 2; ++ni)
            #pragma unroll
            for (int ks = 0; ks < 2; ++ks)
                bB[ni][ks] = LDF(buf, qb, bb + 32 + ni * 16 + fr, ks);
        BAR;
        __builtin_amdgcn_s_setprio(1);
        MFMA_Q(0, 1, bB);
        __builtin_amdgcn_s_setprio(0);
        BAR;
        // ---- phase 2: read a(mh1); stage B quarters of kt+2 (into cur buf)
        #pragma unroll
        for (int mi = 0; mi < 4; ++mi)
            #pragma unroll
            for (int ks = 0; ks < 2; ++ks)
                af[mi][ks] = LDF(buf, qa, 64 + mi * 16 + fr, ks);
        if (kt + 2 < NT) {
            STAGE(B, col0,       (kt + 2) << 6, buf, 2);
            STAGE(B, col0 + 128, (kt + 2) << 6, buf, 3);
        }
        BAR;
        __builtin_amdgcn_s_setprio(1);
        MFMA_Q(1, 1, bB);
        __builtin_amdgcn_s_setprio(0);
        BAR;
        // ---- phase 3: stage A-q0 of kt+2; counted vmcnt; MFMA
        if (kt + 2 < NT) {
            STAGE(A, row0, (kt + 2) << 6, buf, 0);
            asm volatile("s_waitcnt vmcnt(6)" ::: "memory");
        } else {
            asm volatile("s_waitcnt vmcnt(0)" ::: "memory");
        }
        BAR;
        __builtin_amdgcn_s_setprio(1);
        MFMA_Q(1, 0, bA);
        __builtin_amdgcn_s_setprio(0);
        BAR;
    }
#undef MFMA_Q

    // epilogue: C/D layout col=lane&15, row=(lane>>4)*4+j
    const int cr = (l >> 4) * 4;
    const int cc = l & 15;
    #pragma unroll
    for (int m = 0; m < 8; ++m) {
        #pragma unroll
        for (int n = 0; n < 4; ++n) {
            size_t base = (size_t)(row0 + wm * 128 + m * 16 + cr) * N +
                          (col0 + wn * 64 + n * 16 + cc);
            #pragma unroll
            for (int j = 0; j < 4; ++j)
                Cb[base + (size_t)j * N] = f2bf(acc[m][n][j]);
        }
    }
}

// ---------------------------------------------------------------------------
// 2b. bf16 MFMA GEMM (TN), m97 structure (used for GEMM2: f32 out + residual)
// ---------------------------------------------------------------------------
__global__ __launch_bounds__(256) void gemm_bf16(const short* __restrict__ A,
                                                 const short* __restrict__ B,
                                                 const float* __restrict__ add,
                                                 float* __restrict__ Cf,
                                                 unsigned short* __restrict__ Cb,
                                                 int M, int N, int K) {
    __shared__ short As[128 * 32];
    __shared__ short Bs[128 * 32];

    const int tid = threadIdx.x;
    const int w = tid >> 6;
    const int l = tid & 63;
    const int row0 = blockIdx.y * 128;
    const int col0 = blockIdx.x * 128;
    const int wr = (w >> 1) * 64;
    const int wc = (w & 1) * 64;

    f32x4_t acc[4][4] = {};

    const int srow = w * 32 + (l >> 2);
    const int scol = (l & 3) * 8;
    const short* aSrc = A + (size_t)(row0 + srow) * K + scol;
    const short* bSrc = B + (size_t)(col0 + srow) * K + scol;
    const size_t rstep = (size_t)16 * K;

    const int fr = l & 15;
    const int fk = (l >> 4) * 8;

    for (int k0 = 0; k0 < K; k0 += 32) {
        GLL16(aSrc + k0,         &As[(w * 32) * 32]);
        GLL16(aSrc + k0 + rstep, &As[(w * 32 + 16) * 32]);
        GLL16(bSrc + k0,         &Bs[(w * 32) * 32]);
        GLL16(bSrc + k0 + rstep, &Bs[(w * 32 + 16) * 32]);
        __syncthreads();

        bf16x8_t af[4], bfr[4];
        #pragma unroll
        for (int m = 0; m < 4; ++m)
            af[m] = *reinterpret_cast<const bf16x8_t*>(&As[(wr + m * 16 + fr) * 32 + fk]);
        #pragma unroll
        for (int n = 0; n < 4; ++n)
            bfr[n] = *reinterpret_cast<const bf16x8_t*>(&Bs[(wc + n * 16 + fr) * 32 + fk]);

        #pragma unroll
        for (int m = 0; m < 4; ++m)
            #pragma unroll
            for (int n = 0; n < 4; ++n)
                acc[m][n] = __builtin_amdgcn_mfma_f32_16x16x32_bf16(
                    af[m], bfr[n], acc[m][n], 0, 0, 0);
        __syncthreads();
    }

    const int cr = (l >> 4) * 4;
    const int cc = l & 15;
    #pragma unroll
    for (int m = 0; m < 4; ++m) {
        #pragma unroll
        for (int n = 0; n < 4; ++n) {
            size_t base = (size_t)(row0 + wr + m * 16 + cr) * N + (col0 + wc + n * 16 + cc);
            #pragma unroll
            for (int j = 0; j < 4; ++j) {
                float v = acc[m][n][j];
                if (Cb) {
                    Cb[base + (size_t)j * N] = f2bf(v);
                } else {
                    if (add) v += add[base + (size_t)j * N];
                    Cf[base + (size_t)j * N] = v;
                }
            }
        }
    }
}

// ---------------------------------------------------------------------------
// 3. V = x_part @ Bm^T via MFMA. One wave per 16 rows.
// ---------------------------------------------------------------------------
__global__ __launch_bounds__(64) void v_mfma(const unsigned short* __restrict__ xz,
                                             const unsigned short* __restrict__ Bmb,
                                             float* __restrict__ V) {
    const int l = threadIdx.x;
    const int r0 = blockIdx.x * 16;
    const int fr = l & 15;
    const int fk = (l >> 4) * 8;

    const unsigned short* aP = xz + (size_t)(r0 + fr) * (2 * D_INNER) + fk;
    const unsigned short* bP = Bmb + fr * D_INNER + fk;

    f32x4_t acc = {};
    #pragma unroll 4
    for (int k0 = 0; k0 < D_INNER; k0 += 32) {
        bf16x8_t a = *reinterpret_cast<const bf16x8_t*>(aP + k0);
        bf16x8_t b = *reinterpret_cast<const bf16x8_t*>(bP + k0);
        acc = __builtin_amdgcn_mfma_f32_16x16x32_bf16(a, b, acc, 0, 0, 0);
    }

    const int cr = (l >> 4) * 4;
    const int cc = l & 15;
    #pragma unroll
    for (int j = 0; j < 4; ++j)
        V[(size_t)(r0 + cr + j) * D_STATE + cc] = acc[j];
}

// ---------------------------------------------------------------------------
// 4a. check_a: flag = (A != I) ? 1 : 0
// ---------------------------------------------------------------------------
__global__ __launch_bounds__(256) void check_a(const float* __restrict__ A,
                                               int* __restrict__ flag) {
    const int i = threadIdx.x;
    if (i == 0) *flag = 0;
    __syncthreads();
    const float ex = ((i >> 4) == (i & 15)) ? 1.0f : 0.0f;
    unsigned long long bad = __ballot(A[i] != ex);
    if ((i & 63) == 0 && bad) atomicOr(flag, 1);
}

// ---------------------------------------------------------------------------
// 4b. Parallel inclusive cumsum over t (A == I path).
// ---------------------------------------------------------------------------
__global__ __launch_bounds__(256) void scan_par(const float* __restrict__ V,
                                                float* __restrict__ S,
                                                const int* __restrict__ flag) {
    if (*flag) return;
    const int p = blockIdx.x;        // 0..31
    const int b = p >> 4, s = p & 15;
    const int tid = threadIdx.x;
    const float* vb = V + (size_t)b * SEQ * D_STATE + s;
    float* sb = S + (size_t)b * SEQ * D_STATE + s;

    const int t0 = tid * 16;
    float v[16];
    float run = 0.0f;
    #pragma unroll
    for (int j = 0; j < 16; ++j) {
        run += vb[(size_t)(t0 + j) * D_STATE];
        v[j] = run;
    }

    const float tot = run;
    float sc = tot;
    #pragma unroll
    for (int off = 1; off < 64; off <<= 1) {
        float n = __shfl_up(sc, off, 64);
        if ((tid & 63) >= off) sc += n;
    }
    __shared__ float wtot[4];
    if ((tid & 63) == 63) wtot[tid >> 6] = sc;
    __syncthreads();
    float woff = 0.0f;
    #pragma unroll
    for (int w2 = 0; w2 < 4; ++w2)
        if (w2 < (tid >> 6)) woff += wtot[w2];
    const float excl = sc - tot + woff;

    #pragma unroll
    for (int j = 0; j < 16; ++j)
        sb[(size_t)(t0 + j) * D_STATE] = v[j] + excl;
}

// ---------------------------------------------------------------------------
// 4c. Sequential general-A scan (fallback; no-op when A == I)
// ---------------------------------------------------------------------------
#define SCAN_CHUNK 256

__global__ __launch_bounds__(64) void scan_seq(const float* __restrict__ V,
                                               const float* __restrict__ A,
                                               float* __restrict__ S,
                                               const int* __restrict__ flag) {
    if (*flag == 0) return;
    __shared__ float Al[D_STATE * D_STATE];
    __shared__ float Vl[2 * SCAN_CHUNK * D_STATE];
    __shared__ float Sl[2 * SCAN_CHUNK * D_STATE];

    const int tid = threadIdx.x;
    for (int i = tid; i < D_STATE * D_STATE; i += 64) Al[i] = A[i];
    __syncthreads();

    float st = 0.0f;
    const int bb = (tid >> 4) & 1;
    const int ss = tid & 15;

    for (int t0 = 0; t0 < SEQ; t0 += SCAN_CHUNK) {
        for (int idx = tid; idx < 2 * SCAN_CHUNK * D_STATE; idx += 64) {
            int b = idx >> 12;
            int rem = idx & 4095;
            Vl[idx] = V[((size_t)(b * SEQ + t0) * D_STATE) + rem];
        }
        __syncthreads();

        if (tid < 32) {
            float* vb = Vl + bb * SCAN_CHUNK * D_STATE + ss;
            float* sb = Sl + bb * SCAN_CHUNK * D_STATE + ss;
            for (int t = 0; t < SCAN_CHUNK; ++t) {
                float ns = vb[t * D_STATE];
                #pragma unroll
                for (int s2 = 0; s2 < D_STATE; ++s2) {
                    float other = __shfl(st, (tid & 16) | s2, 64);
                    ns = fmaf(Al[ss * D_STATE + s2], other, ns);
                }
                st = ns;
                sb[t * D_STATE] = st;
            }
        }
        __syncthreads();

        for (int idx = tid; idx < 2 * SCAN_CHUNK * D_STATE; idx += 64) {
            int b = idx >> 12;
            int rem = idx & 4095;
            S[((size_t)(b * SEQ + t0) * D_STATE) + rem] = Sl[idx];
        }
        __syncthreads();
    }
}

// ---------------------------------------------------------------------------
// 5. y = (silu(conv(x_part)) + S @ Cm) * sigmoid(z)  -> bf16 output
// ---------------------------------------------------------------------------
__global__ __launch_bounds__(256) void y_kernel(const unsigned short* __restrict__ xz,
                                                const float* __restrict__ S,
                                                const float* __restrict__ Cm,
                                                const float* __restrict__ convw,
                                                const float* __restrict__ convb,
                                                unsigned short* __restrict__ y) {
    const int tid = threadIdx.x;
    const int i0 = blockIdx.x * 512 + tid * 2;
    const int r0 = blockIdx.y * 64;
    const int tb0 = r0 & (SEQ - 1);

    const float4 w0 = *reinterpret_cast<const float4*>(&convw[i0 * D_CONV]);
    const float4 w1 = *reinterpret_cast<const float4*>(&convw[(i0 + 1) * D_CONV]);
    const float cb0 = convb[i0], cb1 = convb[i0 + 1];
    float cm0[D_STATE], cm1[D_STATE];
    #pragma unroll
    for (int s = 0; s < D_STATE; ++s) {
        float2 c = *reinterpret_cast<const float2*>(&Cm[s * D_INNER + i0]);
        cm0[s] = c.x; cm1[s] = c.y;
    }

    float2 xm1 = make_float2(0.f, 0.f), xm2 = xm1, xm3 = xm1;
    if (tb0 >= 1) { ushort2 u = *reinterpret_cast<const ushort2*>(&xz[(size_t)(r0 - 1) * (2 * D_INNER) + i0]); xm1 = make_float2(bf2f(u.x), bf2f(u.y)); }
    if (tb0 >= 2) { ushort2 u = *reinterpret_cast<const ushort2*>(&xz[(size_t)(r0 - 2) * (2 * D_INNER) + i0]); xm2 = make_float2(bf2f(u.x), bf2f(u.y)); }
    if (tb0 >= 3) { ushort2 u = *reinterpret_cast<const ushort2*>(&xz[(size_t)(r0 - 3) * (2 * D_INNER) + i0]); xm3 = make_float2(bf2f(u.x), bf2f(u.y)); }

    for (int r = r0; r < r0 + 64; ++r) {
        const ushort2 xu = *reinterpret_cast<const ushort2*>(&xz[(size_t)r * (2 * D_INNER) + i0]);
        const ushort2 zu = *reinterpret_cast<const ushort2*>(&xz[(size_t)r * (2 * D_INNER) + D_INNER + i0]);
        const float2 x0 = make_float2(bf2f(xu.x), bf2f(xu.y));

        float a0 = cb0;
        a0 = fmaf(w0.x, xm3.x, a0); a0 = fmaf(w0.y, xm2.x, a0);
        a0 = fmaf(w0.z, xm1.x, a0); a0 = fmaf(w0.w, x0.x, a0);
        float a1 = cb1;
        a1 = fmaf(w1.x, xm3.y, a1); a1 = fmaf(w1.y, xm2.y, a1);
        a1 = fmaf(w1.z, xm1.y, a1); a1 = fmaf(w1.w, x0.y, a1);

        const float xc0 = a0 / (1.0f + expf(-a0));
        const float xc1 = a1 / (1.0f + expf(-a1));

        const float4* Sp = reinterpret_cast<const float4*>(S + (size_t)r * D_STATE);
        const float4 s0 = Sp[0], s1 = Sp[1], s2 = Sp[2], s3 = Sp[3];
        const float sv[D_STATE] = {s0.x, s0.y, s0.z, s0.w, s1.x, s1.y, s1.z, s1.w,
                                   s2.x, s2.y, s2.z, s2.w, s3.x, s3.y, s3.z, s3.w};
        float sc0 = 0.f, sc1 = 0.f;
        #pragma unroll
        for (int s = 0; s < D_STATE; ++s) {
            sc0 = fmaf(sv[s], cm0[s], sc0);
            sc1 = fmaf(sv[s], cm1[s], sc1);
        }

        const float z0 = bf2f(zu.x), z1 = bf2f(zu.y);
        const float g0 = 1.0f / (1.0f + expf(-z0));
        const float g1 = 1.0f / (1.0f + expf(-z1));

        ushort2 o;
        o.x = f2bf((xc0 + sc0) * g0);
        o.y = f2bf((xc1 + sc1) * g1);
        *reinterpret_cast<ushort2*>(&y[(size_t)r * D_INNER + i0]) = o;

        xm3 = xm2; xm2 = xm1; xm1 = x0;
    }
}

// ---------------------------------------------------------------------------
// launch
// ---------------------------------------------------------------------------
extern "C" void kernel_launch(void* const* d_in, const int* in_sizes, int n_in,
                              void* d_out, int out_size, void* d_ws, size_t ws_size,
                              hipStream_t stream) {
    const float* x      = (const float*)d_in[0];
    const float* ln_g   = (const float*)d_in[1];
    const float* ln_b   = (const float*)d_in[2];
    const float* W_in   = (const float*)d_in[3];
    const float* conv_w = (const float*)d_in[4];
    const float* conv_b = (const float*)d_in[5];
    const float* W_out  = (const float*)d_in[6];
    const float* A      = (const float*)d_in[7];
    const float* Bm     = (const float*)d_in[8];
    const float* Cm     = (const float*)d_in[9];
    float* out = (float*)d_out;

    // workspace layout
    float* ws = (float*)d_ws;
    float* V  = ws;                                        // 8192*16 f32
    float* S  = V + (size_t)NROW * D_STATE;                // 8192*16 f32
    int*   flag = (int*)(S + (size_t)NROW * D_STATE);
    unsigned short* xz_bf  = (unsigned short*)(flag + 64); // 8192*4096 bf16
    unsigned short* xn_bf  = xz_bf  + (size_t)NROW * 2 * D_INNER;
    unsigned short* Win_bf = xn_bf  + (size_t)NROW * D_MODEL;
    unsigned short* Wout_bf= Win_bf + (size_t)(2 * D_INNER) * D_MODEL;
    unsigned short* y_bf   = Wout_bf + (size_t)D_MODEL * D_INNER;
    unsigned short* Bm_bf  = y_bf   + (size_t)NROW * D_INNER;

    // weight conversions
    cvt_bf16<<<(2 * D_INNER * D_MODEL) / (256 * 8), 256, 0, stream>>>(W_in, Win_bf);
    cvt_bf16<<<(D_MODEL * D_INNER) / (256 * 8), 256, 0, stream>>>(W_out, Wout_bf);
    cvt_bf16<<<(D_STATE * D_INNER) / (256 * 8), 256, 0, stream>>>(Bm, Bm_bf);

    // 1. LayerNorm -> bf16
    ln_kernel<<<NROW, 256, 0, stream>>>(x, ln_g, ln_b, xn_bf);

    // 2. xz = xn @ W_in^T -> bf16   (M=8192, N=4096, K=1024), 8-phase 256^2
    gemm256_bf16<<<dim3((2 * D_INNER) / 256, NROW / 256), 512, 0, stream>>>(
        (const short*)xn_bf, (const short*)Win_bf, xz_bf,
        NROW, 2 * D_INNER, D_MODEL);

    // 3. V = x_part @ Bm^T  (MFMA, one wave / 16 rows)
    v_mfma<<<NROW / 16, 64, 0, stream>>>(xz_bf, Bm_bf, V);

    // 4. scan: parallel cumsum when A==I, sequential general fallback otherwise
    check_a<<<1, 256, 0, stream>>>(A, flag);
    scan_par<<<32, 256, 0, stream>>>(V, S, flag);
    scan_seq<<<1, 64, 0, stream>>>(V, A, S, flag);

    // 5. y = (silu(conv(x_part)) + S@Cm) * sigmoid(z) -> bf16
    y_kernel<<<dim3(D_INNER / 512, NROW / 64), 256, 0, stream>>>(
        xz_bf, S, Cm, conv_w, conv_b, y_bf);

    // 6. out = x + y @ W_out^T  (M=8192, N=1024, K=2048), m97 structure
    gemm_bf16<<<dim3(D_MODEL / 128, NROW / 128), 256, 0, stream>>>(
        (const short*)y_bf, (const short*)Wout_bf, x, out, nullptr,
        NROW, D_MODEL, D_INNER);
}

// Round 6
// 234.206 us; speedup vs baseline: 6.4702x; 1.0246x over previous
//
#include <hip/hip_runtime.h>
#include <hip/hip_bf16.h>
#include <math.h>

// Problem constants
#define D_MODEL 1024
#define D_STATE 16
#define D_CONV 4
#define D_INNER 2048
#define BATCH 2
#define SEQ 4096
#define NROW (BATCH * SEQ)          // 8192 rows (b*L + t)
#define LN_EPS 1e-5f

typedef __attribute__((ext_vector_type(8))) short  bf16x8_t;   // 8 bf16 (4 VGPRs)
typedef __attribute__((ext_vector_type(4))) float  f32x4_t;    // MFMA accumulator
typedef __attribute__((ext_vector_type(8))) unsigned short u16x8_t;

// round-to-nearest-even f32 -> bf16 (no NaN handling; data is finite)
__device__ inline unsigned short f2bf(float f) {
    unsigned u = __float_as_uint(f);
    u += 0x7fffu + ((u >> 16) & 1u);
    return (unsigned short)(u >> 16);
}
__device__ inline float bf2f(unsigned short u) {
    return __uint_as_float((unsigned)u << 16);
}

#define GLL16(g, l)                                                            \
    __builtin_amdgcn_global_load_lds(                                          \
        (const __attribute__((address_space(1))) void*)(g),                    \
        (__attribute__((address_space(3))) void*)(l), 16, 0, 0)

#define FENCE asm volatile("" ::: "memory")
#define BAR do { FENCE; __builtin_amdgcn_s_barrier(); FENCE; } while (0)

// ---------------------------------------------------------------------------
// 0. fp32 -> bf16 conversion (8 elements / thread)
// ---------------------------------------------------------------------------
__global__ __launch_bounds__(256) void cvt_bf16(const float* __restrict__ in,
                                                unsigned short* __restrict__ out) {
    const int i = blockIdx.x * 256 + threadIdx.x;
    const float4 a = reinterpret_cast<const float4*>(in)[2 * i];
    const float4 b = reinterpret_cast<const float4*>(in)[2 * i + 1];
    u16x8_t p;
    p[0] = f2bf(a.x); p[1] = f2bf(a.y); p[2] = f2bf(a.z); p[3] = f2bf(a.w);
    p[4] = f2bf(b.x); p[5] = f2bf(b.y); p[6] = f2bf(b.z); p[7] = f2bf(b.w);
    reinterpret_cast<u16x8_t*>(out)[i] = p;
}

// ---------------------------------------------------------------------------
// 1. LayerNorm: one block per row of 1024 floats -> bf16 output
// ---------------------------------------------------------------------------
__global__ __launch_bounds__(256) void ln_kernel(const float* __restrict__ x,
                                                 const float* __restrict__ gamma,
                                                 const float* __restrict__ beta,
                                                 unsigned short* __restrict__ xn) {
    const int row = blockIdx.x;
    const int tid = threadIdx.x;
    const float4* xr = reinterpret_cast<const float4*>(x + (size_t)row * D_MODEL);
    float4 v = xr[tid];

    __shared__ float red[8];
    const int lane = tid & 63, wave = tid >> 6;

    float s = v.x + v.y + v.z + v.w;
    #pragma unroll
    for (int off = 32; off > 0; off >>= 1) s += __shfl_down(s, off, 64);
    if (lane == 0) red[wave] = s;
    __syncthreads();
    float mu = (red[0] + red[1] + red[2] + red[3]) * (1.0f / D_MODEL);
    __syncthreads();

    float dx = v.x - mu, dy = v.y - mu, dz = v.z - mu, dw = v.w - mu;
    float ss = dx * dx + dy * dy + dz * dz + dw * dw;
    #pragma unroll
    for (int off = 32; off > 0; off >>= 1) ss += __shfl_down(ss, off, 64);
    if (lane == 0) red[wave] = ss;
    __syncthreads();
    float var = (red[0] + red[1] + red[2] + red[3]) * (1.0f / D_MODEL);
    float rs = rsqrtf(var + LN_EPS);

    const float4 gv = reinterpret_cast<const float4*>(gamma)[tid];
    const float4 bv = reinterpret_cast<const float4*>(beta)[tid];
    ushort4 o;
    o.x = f2bf(dx * rs * gv.x + bv.x);
    o.y = f2bf(dy * rs * gv.y + bv.y);
    o.z = f2bf(dz * rs * gv.z + bv.z);
    o.w = f2bf(dw * rs * gv.w + bv.w);
    reinterpret_cast<ushort4*>(xn + (size_t)row * D_MODEL)[tid] = o;
}

// ---------------------------------------------------------------------------
// 2a. 256x256 8-phase bf16 MFMA GEMM (TN), bf16 output.
//     BK=64, 8 waves (2Mx4N), 128 KiB LDS dbuf, counted vmcnt(6),
//     raw s_barrier, setprio around MFMA clusters.
//     Swizzle: c ^= (r&7)<<3 (elements) — full 3-row-bit XOR so the 16
//     consecutive-row ds_read_b128 lanes hit 8 distinct 16B slots
//     (2 lanes/bank = free). Applied on BOTH stage-source and read.
// ---------------------------------------------------------------------------
__global__ __launch_bounds__(512) void gemm256_bf16(const short* __restrict__ A,
                                                    const short* __restrict__ B,
                                                    unsigned short* __restrict__ Cb,
                                                    int M, int N, int K) {
    __shared__ short lds[2 * 4 * 8192];   // 128 KiB

    const int tid = threadIdx.x;
    const int w = tid >> 6, l = tid & 63;
    const int row0 = blockIdx.y * 256;
    const int col0 = blockIdx.x * 256;
    const int wm = w >> 2;               // 0..1  (M wave)
    const int wn = w & 3;                // 0..3  (N wave)
    const int fr = l & 15;
    const int fc = (l >> 4) * 8;         // 0,8,16,24
    const int NT = K >> 6;               // K-tiles of 64

    const int qa = wm;                   // wave's A quarter
    const int qb = 2 + (wn >> 1);        // wave's B quarter
    const int bb = (wn & 1) * 64;        // wave's row base within B quarter

    // stage one 128x64 half-tile (quarter q of buffer buf); linear LDS dest,
    // source col pre-swizzled with c ^= (r&7)<<3.
    auto STAGE = [&](const short* __restrict__ G, int growbase, int k0,
                     int buf, int q) {
        #pragma unroll
        for (int j = 0; j < 2; ++j) {
            const int e = ((j * 8 + w) << 9) + l * 8;    // element in quarter
            const int r = e >> 6;
            const int c = (e & 63) ^ ((r & 7) << 3);
            GLL16(G + (size_t)(growbase + r) * K + k0 + c,
                  &lds[buf * 32768 + q * 8192 + ((j * 8 + w) << 9)]);
        }
    };
    // read one MFMA fragment (8 bf16) at quarter-local row r, k-substep ks
    auto LDF = [&](int buf, int q, int r, int ks) -> bf16x8_t {
        const int c = (ks * 32 + fc) ^ ((r & 7) << 3);
        return *reinterpret_cast<const bf16x8_t*>(
            &lds[buf * 32768 + q * 8192 + r * 64 + c]);
    };

    f32x4_t acc[8][4] = {};
    bf16x8_t af[4][2], bA[2][2], bB[2][2];

#define MFMA_Q(mh, nh, bfr)                                                    \
    do {                                                                       \
        _Pragma("unroll")                                                      \
        for (int mi = 0; mi < 4; ++mi)                                         \
            _Pragma("unroll")                                                  \
            for (int ni = 0; ni < 2; ++ni)                                     \
                _Pragma("unroll")                                              \
                for (int ks = 0; ks < 2; ++ks)                                 \
                    acc[(mh) * 4 + mi][(nh) * 2 + ni] =                        \
                        __builtin_amdgcn_mfma_f32_16x16x32_bf16(               \
                            af[mi][ks], bfr[ni][ks],                           \
                            acc[(mh) * 4 + mi][(nh) * 2 + ni], 0, 0, 0);       \
    } while (0)

    // ---- prologue: k0 all 4 quarters (buf0); k1 B quarters + A-q0 (buf1)
    STAGE(A, row0,       0, 0, 0);
    STAGE(A, row0 + 128, 0, 0, 1);
    STAGE(B, col0,       0, 0, 2);
    STAGE(B, col0 + 128, 0, 0, 3);
    if (NT > 1) {
        STAGE(B, col0,       64, 1, 2);
        STAGE(B, col0 + 128, 64, 1, 3);
        STAGE(A, row0,       64, 1, 0);
        asm volatile("s_waitcnt vmcnt(6)" ::: "memory");
    } else {
        asm volatile("s_waitcnt vmcnt(0)" ::: "memory");
    }
    BAR;

    for (int kt = 0; kt < NT; ++kt) {
        const int buf = kt & 1, nbuf = buf ^ 1;
        // ---- phase 0: read a(mh0)+bA(nh0); stage A-q1 of kt+1
        #pragma unroll
        for (int mi = 0; mi < 4; ++mi)
            #pragma unroll
            for (int ks = 0; ks < 2; ++ks)
                af[mi][ks] = LDF(buf, qa, mi * 16 + fr, ks);
        #pragma unroll
        for (int ni = 0; ni < 2; ++ni)
            #pragma unroll
            for (int ks = 0; ks < 2; ++ks)
                bA[ni][ks] = LDF(buf, qb, bb + ni * 16 + fr, ks);
        if (kt + 1 < NT) STAGE(A, row0 + 128, (kt + 1) << 6, nbuf, 1);
        BAR;
        __builtin_amdgcn_s_setprio(1);
        MFMA_Q(0, 0, bA);
        __builtin_amdgcn_s_setprio(0);
        BAR;
        // ---- phase 1: read bB(nh1)
        #pragma unroll
        for (int ni = 0; ni < 2; ++ni)
            #pragma unroll
            for (int ks = 0; ks < 2; ++ks)
                bB[ni][ks] = LDF(buf, qb, bb + 32 + ni * 16 + fr, ks);
        BAR;
        __builtin_amdgcn_s_setprio(1);
        MFMA_Q(0, 1, bB);
        __builtin_amdgcn_s_setprio(0);
        BAR;
        // ---- phase 2: read a(mh1); stage B quarters of kt+2 (into cur buf)
        #pragma unroll
        for (int mi = 0; mi < 4; ++mi)
            #pragma unroll
            for (int ks = 0; ks < 2; ++ks)
                af[mi][ks] = LDF(buf, qa, 64 + mi * 16 + fr, ks);
        if (kt + 2 < NT) {
            STAGE(B, col0,       (kt + 2) << 6, buf, 2);
            STAGE(B, col0 + 128, (kt + 2) << 6, buf, 3);
        }
        BAR;
        __builtin_amdgcn_s_setprio(1);
        MFMA_Q(1, 1, bB);
        __builtin_amdgcn_s_setprio(0);
        BAR;
        // ---- phase 3: stage A-q0 of kt+2; counted vmcnt; MFMA
        if (kt + 2 < NT) {
            STAGE(A, row0, (kt + 2) << 6, buf, 0);
            asm volatile("s_waitcnt vmcnt(6)" ::: "memory");
        } else {
            asm volatile("s_waitcnt vmcnt(0)" ::: "memory");
        }
        BAR;
        __builtin_amdgcn_s_setprio(1);
        MFMA_Q(1, 0, bA);
        __builtin_amdgcn_s_setprio(0);
        BAR;
    }
#undef MFMA_Q

    // epilogue: C/D layout col=lane&15, row=(lane>>4)*4+j
    const int cr = (l >> 4) * 4;
    const int cc = l & 15;
    #pragma unroll
    for (int m = 0; m < 8; ++m) {
        #pragma unroll
        for (int n = 0; n < 4; ++n) {
            size_t base = (size_t)(row0 + wm * 128 + m * 16 + cr) * N +
                          (col0 + wn * 64 + n * 16 + cc);
            #pragma unroll
            for (int j = 0; j < 4; ++j)
                Cb[base + (size_t)j * N] = f2bf(acc[m][n][j]);
        }
    }
}

// ---------------------------------------------------------------------------
// 2b. bf16 MFMA GEMM (TN), m97 structure (GEMM2: f32 out + residual).
//     Swizzle c ^= (r&3)<<3 (4 slots per 64B row) on stage-source and read.
// ---------------------------------------------------------------------------
__global__ __launch_bounds__(256) void gemm_bf16(const short* __restrict__ A,
                                                 const short* __restrict__ B,
                                                 const float* __restrict__ add,
                                                 float* __restrict__ Cf,
                                                 unsigned short* __restrict__ Cb,
                                                 int M, int N, int K) {
    __shared__ short As[128 * 32];
    __shared__ short Bs[128 * 32];

    const int tid = threadIdx.x;
    const int w = tid >> 6;
    const int l = tid & 63;
    const int row0 = blockIdx.y * 128;
    const int col0 = blockIdx.x * 128;
    const int wr = (w >> 1) * 64;
    const int wc = (w & 1) * 64;

    f32x4_t acc[4][4] = {};

    const int srow = w * 32 + (l >> 2);
    const int scol = ((l & 3) * 8) ^ ((srow & 3) << 3);   // pre-swizzled source
    const short* aSrc = A + (size_t)(row0 + srow) * K + scol;
    const short* bSrc = B + (size_t)(col0 + srow) * K + scol;
    const size_t rstep = (size_t)16 * K;

    const int fr = l & 15;
    const int fk0 = (l >> 4) * 8;
    const int fk = fk0 ^ ((fr & 3) << 3);                 // swizzled read col

    for (int k0 = 0; k0 < K; k0 += 32) {
        GLL16(aSrc + k0,         &As[(w * 32) * 32]);
        GLL16(aSrc + k0 + rstep, &As[(w * 32 + 16) * 32]);
        GLL16(bSrc + k0,         &Bs[(w * 32) * 32]);
        GLL16(bSrc + k0 + rstep, &Bs[(w * 32 + 16) * 32]);
        __syncthreads();

        bf16x8_t af[4], bfr[4];
        #pragma unroll
        for (int m = 0; m < 4; ++m)
            af[m] = *reinterpret_cast<const bf16x8_t*>(&As[(wr + m * 16 + fr) * 32 + fk]);
        #pragma unroll
        for (int n = 0; n < 4; ++n)
            bfr[n] = *reinterpret_cast<const bf16x8_t*>(&Bs[(wc + n * 16 + fr) * 32 + fk]);

        #pragma unroll
        for (int m = 0; m < 4; ++m)
            #pragma unroll
            for (int n = 0; n < 4; ++n)
                acc[m][n] = __builtin_amdgcn_mfma_f32_16x16x32_bf16(
                    af[m], bfr[n], acc[m][n], 0, 0, 0);
        __syncthreads();
    }

    const int cr = (l >> 4) * 4;
    const int cc = l & 15;
    #pragma unroll
    for (int m = 0; m < 4; ++m) {
        #pragma unroll
        for (int n = 0; n < 4; ++n) {
            size_t base = (size_t)(row0 + wr + m * 16 + cr) * N + (col0 + wc + n * 16 + cc);
            #pragma unroll
            for (int j = 0; j < 4; ++j) {
                float v = acc[m][n][j];
                if (Cb) {
                    Cb[base + (size_t)j * N] = f2bf(v);
                } else {
                    if (add) v += add[base + (size_t)j * N];
                    Cf[base + (size_t)j * N] = v;
                }
            }
        }
    }
}

// ---------------------------------------------------------------------------
// 3. V = x_part @ Bm^T via MFMA. One wave per 16 rows.
// ---------------------------------------------------------------------------
__global__ __launch_bounds__(64) void v_mfma(const unsigned short* __restrict__ xz,
                                             const unsigned short* __restrict__ Bmb,
                                             float* __restrict__ V) {
    const int l = threadIdx.x;
    const int r0 = blockIdx.x * 16;
    const int fr = l & 15;
    const int fk = (l >> 4) * 8;

    const unsigned short* aP = xz + (size_t)(r0 + fr) * (2 * D_INNER) + fk;
    const unsigned short* bP = Bmb + fr * D_INNER + fk;

    f32x4_t acc = {};
    #pragma unroll 4
    for (int k0 = 0; k0 < D_INNER; k0 += 32) {
        bf16x8_t a = *reinterpret_cast<const bf16x8_t*>(aP + k0);
        bf16x8_t b = *reinterpret_cast<const bf16x8_t*>(bP + k0);
        acc = __builtin_amdgcn_mfma_f32_16x16x32_bf16(a, b, acc, 0, 0, 0);
    }

    const int cr = (l >> 4) * 4;
    const int cc = l & 15;
    #pragma unroll
    for (int j = 0; j < 4; ++j)
        V[(size_t)(r0 + cr + j) * D_STATE + cc] = acc[j];
}

// ---------------------------------------------------------------------------
// 4a. check_a: flag = (A != I) ? 1 : 0
// ---------------------------------------------------------------------------
__global__ __launch_bounds__(256) void check_a(const float* __restrict__ A,
                                               int* __restrict__ flag) {
    const int i = threadIdx.x;
    if (i == 0) *flag = 0;
    __syncthreads();
    const float ex = ((i >> 4) == (i & 15)) ? 1.0f : 0.0f;
    unsigned long long bad = __ballot(A[i] != ex);
    if ((i & 63) == 0 && bad) atomicOr(flag, 1);
}

// ---------------------------------------------------------------------------
// 4b. Parallel inclusive cumsum over t (A == I path).
// ---------------------------------------------------------------------------
__global__ __launch_bounds__(256) void scan_par(const float* __restrict__ V,
                                                float* __restrict__ S,
                                                const int* __restrict__ flag) {
    if (*flag) return;
    const int p = blockIdx.x;        // 0..31
    const int b = p >> 4, s = p & 15;
    const int tid = threadIdx.x;
    const float* vb = V + (size_t)b * SEQ * D_STATE + s;
    float* sb = S + (size_t)b * SEQ * D_STATE + s;

    const int t0 = tid * 16;
    float v[16];
    float run = 0.0f;
    #pragma unroll
    for (int j = 0; j < 16; ++j) {
        run += vb[(size_t)(t0 + j) * D_STATE];
        v[j] = run;
    }

    const float tot = run;
    float sc = tot;
    #pragma unroll
    for (int off = 1; off < 64; off <<= 1) {
        float n = __shfl_up(sc, off, 64);
        if ((tid & 63) >= off) sc += n;
    }
    __shared__ float wtot[4];
    if ((tid & 63) == 63) wtot[tid >> 6] = sc;
    __syncthreads();
    float woff = 0.0f;
    #pragma unroll
    for (int w2 = 0; w2 < 4; ++w2)
        if (w2 < (tid >> 6)) woff += wtot[w2];
    const float excl = sc - tot + woff;

    #pragma unroll
    for (int j = 0; j < 16; ++j)
        sb[(size_t)(t0 + j) * D_STATE] = v[j] + excl;
}

// ---------------------------------------------------------------------------
// 4c. Sequential general-A scan (fallback; no-op when A == I)
// ---------------------------------------------------------------------------
#define SCAN_CHUNK 256

__global__ __launch_bounds__(64) void scan_seq(const float* __restrict__ V,
                                               const float* __restrict__ A,
                                               float* __restrict__ S,
                                               const int* __restrict__ flag) {
    if (*flag == 0) return;
    __shared__ float Al[D_STATE * D_STATE];
    __shared__ float Vl[2 * SCAN_CHUNK * D_STATE];
    __shared__ float Sl[2 * SCAN_CHUNK * D_STATE];

    const int tid = threadIdx.x;
    for (int i = tid; i < D_STATE * D_STATE; i += 64) Al[i] = A[i];
    __syncthreads();

    float st = 0.0f;
    const int bb = (tid >> 4) & 1;
    const int ss = tid & 15;

    for (int t0 = 0; t0 < SEQ; t0 += SCAN_CHUNK) {
        for (int idx = tid; idx < 2 * SCAN_CHUNK * D_STATE; idx += 64) {
            int b = idx >> 12;
            int rem = idx & 4095;
            Vl[idx] = V[((size_t)(b * SEQ + t0) * D_STATE) + rem];
        }
        __syncthreads();

        if (tid < 32) {
            float* vb = Vl + bb * SCAN_CHUNK * D_STATE + ss;
            float* sb = Sl + bb * SCAN_CHUNK * D_STATE + ss;
            for (int t = 0; t < SCAN_CHUNK; ++t) {
                float ns = vb[t * D_STATE];
                #pragma unroll
                for (int s2 = 0; s2 < D_STATE; ++s2) {
                    float other = __shfl(st, (tid & 16) | s2, 64);
                    ns = fmaf(Al[ss * D_STATE + s2], other, ns);
                }
                st = ns;
                sb[t * D_STATE] = st;
            }
        }
        __syncthreads();

        for (int idx = tid; idx < 2 * SCAN_CHUNK * D_STATE; idx += 64) {
            int b = idx >> 12;
            int rem = idx & 4095;
            S[((size_t)(b * SEQ + t0) * D_STATE) + rem] = Sl[idx];
        }
        __syncthreads();
    }
}

// ---------------------------------------------------------------------------
// 5. y = (silu(conv(x_part)) + S @ Cm) * sigmoid(z)  -> bf16 output
// ---------------------------------------------------------------------------
__global__ __launch_bounds__(256) void y_kernel(const unsigned short* __restrict__ xz,
                                                const float* __restrict__ S,
                                                const float* __restrict__ Cm,
                                                const float* __restrict__ convw,
                                                const float* __restrict__ convb,
                                                unsigned short* __restrict__ y) {
    const int tid = threadIdx.x;
    const int i0 = blockIdx.x * 512 + tid * 2;
    const int r0 = blockIdx.y * 64;
    const int tb0 = r0 & (SEQ - 1);

    const float4 w0 = *reinterpret_cast<const float4*>(&convw[i0 * D_CONV]);
    const float4 w1 = *reinterpret_cast<const float4*>(&convw[(i0 + 1) * D_CONV]);
    const float cb0 = convb[i0], cb1 = convb[i0 + 1];
    float cm0[D_STATE], cm1[D_STATE];
    #pragma unroll
    for (int s = 0; s < D_STATE; ++s) {
        float2 c = *reinterpret_cast<const float2*>(&Cm[s * D_INNER + i0]);
        cm0[s] = c.x; cm1[s] = c.y;
    }

    float2 xm1 = make_float2(0.f, 0.f), xm2 = xm1, xm3 = xm1;
    if (tb0 >= 1) { ushort2 u = *reinterpret_cast<const ushort2*>(&xz[(size_t)(r0 - 1) * (2 * D_INNER) + i0]); xm1 = make_float2(bf2f(u.x), bf2f(u.y)); }
    if (tb0 >= 2) { ushort2 u = *reinterpret_cast<const ushort2*>(&xz[(size_t)(r0 - 2) * (2 * D_INNER) + i0]); xm2 = make_float2(bf2f(u.x), bf2f(u.y)); }
    if (tb0 >= 3) { ushort2 u = *reinterpret_cast<const ushort2*>(&xz[(size_t)(r0 - 3) * (2 * D_INNER) + i0]); xm3 = make_float2(bf2f(u.x), bf2f(u.y)); }

    for (int r = r0; r < r0 + 64; ++r) {
        const ushort2 xu = *reinterpret_cast<const ushort2*>(&xz[(size_t)r * (2 * D_INNER) + i0]);
        const ushort2 zu = *reinterpret_cast<const ushort2*>(&xz[(size_t)r * (2 * D_INNER) + D_INNER + i0]);
        const float2 x0 = make_float2(bf2f(xu.x), bf2f(xu.y));

        float a0 = cb0;
        a0 = fmaf(w0.x, xm3.x, a0); a0 = fmaf(w0.y, xm2.x, a0);
        a0 = fmaf(w0.z, xm1.x, a0); a0 = fmaf(w0.w, x0.x, a0);
        float a1 = cb1;
        a1 = fmaf(w1.x, xm3.y, a1); a1 = fmaf(w1.y, xm2.y, a1);
        a1 = fmaf(w1.z, xm1.y, a1); a1 = fmaf(w1.w, x0.y, a1);

        const float xc0 = a0 / (1.0f + expf(-a0));
        const float xc1 = a1 / (1.0f + expf(-a1));

        const float4* Sp = reinterpret_cast<const float4*>(S + (size_t)r * D_STATE);
        const float4 s0 = Sp[0], s1 = Sp[1], s2 = Sp[2], s3 = Sp[3];
        const float sv[D_STATE] = {s0.x, s0.y, s0.z, s0.w, s1.x, s1.y, s1.z, s1.w,
                                   s2.x, s2.y, s2.z, s2.w, s3.x, s3.y, s3.z, s3.w};
        float sc0 = 0.f, sc1 = 0.f;
        #pragma unroll
        for (int s = 0; s < D_STATE; ++s) {
            sc0 = fmaf(sv[s], cm0[s], sc0);
            sc1 = fmaf(sv[s], cm1[s], sc1);
        }

        const float z0 = bf2f(zu.x), z1 = bf2f(zu.y);
        const float g0 = 1.0f / (1.0f + expf(-z0));
        const float g1 = 1.0f / (1.0f + expf(-z1));

        ushort2 o;
        o.x = f2bf((xc0 + sc0) * g0);
        o.y = f2bf((xc1 + sc1) * g1);
        *reinterpret_cast<ushort2*>(&y[(size_t)r * D_INNER + i0]) = o;

        xm3 = xm2; xm2 = xm1; xm1 = x0;
    }
}

// ---------------------------------------------------------------------------
// launch
// ---------------------------------------------------------------------------
extern "C" void kernel_launch(void* const* d_in, const int* in_sizes, int n_in,
                              void* d_out, int out_size, void* d_ws, size_t ws_size,
                              hipStream_t stream) {
    const float* x      = (const float*)d_in[0];
    const float* ln_g   = (const float*)d_in[1];
    const float* ln_b   = (const float*)d_in[2];
    const float* W_in   = (const float*)d_in[3];
    const float* conv_w = (const float*)d_in[4];
    const float* conv_b = (const float*)d_in[5];
    const float* W_out  = (const float*)d_in[6];
    const float* A      = (const float*)d_in[7];
    const float* Bm     = (const float*)d_in[8];
    const float* Cm     = (const float*)d_in[9];
    float* out = (float*)d_out;

    // workspace layout
    float* ws = (float*)d_ws;
    float* V  = ws;                                        // 8192*16 f32
    float* S  = V + (size_t)NROW * D_STATE;                // 8192*16 f32
    int*   flag = (int*)(S + (size_t)NROW * D_STATE);
    unsigned short* xz_bf  = (unsigned short*)(flag + 64); // 8192*4096 bf16
    unsigned short* xn_bf  = xz_bf  + (size_t)NROW * 2 * D_INNER;
    unsigned short* Win_bf = xn_bf  + (size_t)NROW * D_MODEL;
    unsigned short* Wout_bf= Win_bf + (size_t)(2 * D_INNER) * D_MODEL;
    unsigned short* y_bf   = Wout_bf + (size_t)D_MODEL * D_INNER;
    unsigned short* Bm_bf  = y_bf   + (size_t)NROW * D_INNER;

    // weight conversions
    cvt_bf16<<<(2 * D_INNER * D_MODEL) / (256 * 8), 256, 0, stream>>>(W_in, Win_bf);
    cvt_bf16<<<(D_MODEL * D_INNER) / (256 * 8), 256, 0, stream>>>(W_out, Wout_bf);
    cvt_bf16<<<(D_STATE * D_INNER) / (256 * 8), 256, 0, stream>>>(Bm, Bm_bf);

    // 1. LayerNorm -> bf16
    ln_kernel<<<NROW, 256, 0, stream>>>(x, ln_g, ln_b, xn_bf);

    // 2. xz = xn @ W_in^T -> bf16   (M=8192, N=4096, K=1024), 8-phase 256^2
    gemm256_bf16<<<dim3((2 * D_INNER) / 256, NROW / 256), 512, 0, stream>>>(
        (const short*)xn_bf, (const short*)Win_bf, xz_bf,
        NROW, 2 * D_INNER, D_MODEL);

    // 3. V = x_part @ Bm^T  (MFMA, one wave / 16 rows)
    v_mfma<<<NROW / 16, 64, 0, stream>>>(xz_bf, Bm_bf, V);

    // 4. scan: parallel cumsum when A==I, sequential general fallback otherwise
    check_a<<<1, 256, 0, stream>>>(A, flag);
    scan_par<<<32, 256, 0, stream>>>(V, S, flag);
    scan_seq<<<1, 64, 0, stream>>>(V, A, S, flag);

    // 5. y = (silu(conv(x_part)) + S@Cm) * sigmoid(z) -> bf16
    y_kernel<<<dim3(D_INNER / 512, NROW / 64), 256, 0, stream>>>(
        xz_bf, S, Cm, conv_w, conv_b, y_bf);

    // 6. out = x + y @ W_out^T  (M=8192, N=1024, K=2048), m97 structure
    gemm_bf16<<<dim3(D_MODEL / 128, NROW / 128), 256, 0, stream>>>(
        (const short*)y_bf, (const short*)Wout_bf, x, out, nullptr,
        NROW, D_MODEL, D_INNER);
}

// Round 7
// 203.218 us; speedup vs baseline: 7.4568x; 1.1525x over previous
//
#include <hip/hip_runtime.h>
#include <hip/hip_bf16.h>
#include <math.h>

// Problem constants
#define D_MODEL 1024
#define D_STATE 16
#define D_CONV 4
#define D_INNER 2048
#define BATCH 2
#define SEQ 4096
#define NROW (BATCH * SEQ)          // 8192 rows (b*L + t)
#define LN_EPS 1e-5f

typedef __attribute__((ext_vector_type(8))) short  bf16x8_t;   // 8 bf16 (4 VGPRs)
typedef __attribute__((ext_vector_type(4))) float  f32x4_t;    // MFMA accumulator
typedef __attribute__((ext_vector_type(8))) unsigned short u16x8_t;

// round-to-nearest-even f32 -> bf16 (no NaN handling; data is finite)
__device__ inline unsigned short f2bf(float f) {
    unsigned u = __float_as_uint(f);
    u += 0x7fffu + ((u >> 16) & 1u);
    return (unsigned short)(u >> 16);
}
__device__ inline float bf2f(unsigned short u) {
    return __uint_as_float((unsigned)u << 16);
}

#define GLL16(g, l)                                                            \
    __builtin_amdgcn_global_load_lds(                                          \
        (const __attribute__((address_space(1))) void*)(g),                    \
        (__attribute__((address_space(3))) void*)(l), 16, 0, 0)

#define FENCE asm volatile("" ::: "memory")
#define BAR do { FENCE; __builtin_amdgcn_s_barrier(); FENCE; } while (0)

// ---------------------------------------------------------------------------
// 0. fp32 -> bf16 conversion for all three weight tensors in ONE launch.
//    Ranges: W_in [0, 4194304), W_out [.., +2097152), Bm [.., +32768).
// ---------------------------------------------------------------------------
__global__ __launch_bounds__(256) void cvt_all(const float* __restrict__ W_in,
                                               const float* __restrict__ W_out,
                                               const float* __restrict__ Bm,
                                               unsigned short* __restrict__ Win_bf,
                                               unsigned short* __restrict__ Wout_bf,
                                               unsigned short* __restrict__ Bm_bf) {
    const long long g = (long long)(blockIdx.x * 256 + threadIdx.x) * 8;
    const long long n1 = (long long)2 * D_INNER * D_MODEL;      // 4194304
    const long long n2 = n1 + (long long)D_MODEL * D_INNER;     // +2097152
    const float* src; unsigned short* dst; long long off;
    if (g < n1)      { src = W_in;  dst = Win_bf;  off = g; }
    else if (g < n2) { src = W_out; dst = Wout_bf; off = g - n1; }
    else             { src = Bm;    dst = Bm_bf;   off = g - n2; }
    const float4 a = *reinterpret_cast<const float4*>(src + off);
    const float4 b = *reinterpret_cast<const float4*>(src + off + 4);
    u16x8_t p;
    p[0] = f2bf(a.x); p[1] = f2bf(a.y); p[2] = f2bf(a.z); p[3] = f2bf(a.w);
    p[4] = f2bf(b.x); p[5] = f2bf(b.y); p[6] = f2bf(b.z); p[7] = f2bf(b.w);
    *reinterpret_cast<u16x8_t*>(dst + off) = p;
}

// ---------------------------------------------------------------------------
// 1. LayerNorm: one block per row of 1024 floats -> bf16 output
// ---------------------------------------------------------------------------
__global__ __launch_bounds__(256) void ln_kernel(const float* __restrict__ x,
                                                 const float* __restrict__ gamma,
                                                 const float* __restrict__ beta,
                                                 unsigned short* __restrict__ xn) {
    const int row = blockIdx.x;
    const int tid = threadIdx.x;
    const float4* xr = reinterpret_cast<const float4*>(x + (size_t)row * D_MODEL);
    float4 v = xr[tid];

    __shared__ float red[8];
    const int lane = tid & 63, wave = tid >> 6;

    float s = v.x + v.y + v.z + v.w;
    #pragma unroll
    for (int off = 32; off > 0; off >>= 1) s += __shfl_down(s, off, 64);
    if (lane == 0) red[wave] = s;
    __syncthreads();
    float mu = (red[0] + red[1] + red[2] + red[3]) * (1.0f / D_MODEL);
    __syncthreads();

    float dx = v.x - mu, dy = v.y - mu, dz = v.z - mu, dw = v.w - mu;
    float ss = dx * dx + dy * dy + dz * dz + dw * dw;
    #pragma unroll
    for (int off = 32; off > 0; off >>= 1) ss += __shfl_down(ss, off, 64);
    if (lane == 0) red[wave] = ss;
    __syncthreads();
    float var = (red[0] + red[1] + red[2] + red[3]) * (1.0f / D_MODEL);
    float rs = rsqrtf(var + LN_EPS);

    const float4 gv = reinterpret_cast<const float4*>(gamma)[tid];
    const float4 bv = reinterpret_cast<const float4*>(beta)[tid];
    ushort4 o;
    o.x = f2bf(dx * rs * gv.x + bv.x);
    o.y = f2bf(dy * rs * gv.y + bv.y);
    o.z = f2bf(dz * rs * gv.z + bv.z);
    o.w = f2bf(dw * rs * gv.w + bv.w);
    reinterpret_cast<ushort4*>(xn + (size_t)row * D_MODEL)[tid] = o;
}

// ---------------------------------------------------------------------------
// 2a. 256x256 8-phase bf16 MFMA GEMM (TN), bf16 output. (GEMM1)
// ---------------------------------------------------------------------------
__global__ __launch_bounds__(512) void gemm256_bf16(const short* __restrict__ A,
                                                    const short* __restrict__ B,
                                                    unsigned short* __restrict__ Cb,
                                                    int M, int N, int K) {
    __shared__ short lds[2 * 4 * 8192];   // 128 KiB

    const int tid = threadIdx.x;
    const int w = tid >> 6, l = tid & 63;
    const int row0 = blockIdx.y * 256;
    const int col0 = blockIdx.x * 256;
    const int wm = w >> 2;               // 0..1  (M wave)
    const int wn = w & 3;                // 0..3  (N wave)
    const int fr = l & 15;
    const int fc = (l >> 4) * 8;         // 0,8,16,24
    const int NT = K >> 6;               // K-tiles of 64

    const int qa = wm;                   // wave's A quarter
    const int qb = 2 + (wn >> 1);        // wave's B quarter
    const int bb = (wn & 1) * 64;        // wave's row base within B quarter

    auto STAGE = [&](const short* __restrict__ G, int growbase, int k0,
                     int buf, int q) {
        #pragma unroll
        for (int j = 0; j < 2; ++j) {
            const int e = ((j * 8 + w) << 9) + l * 8;    // element in quarter
            const int r = e >> 6;
            const int c = (e & 63) ^ ((r & 7) << 3);
            GLL16(G + (size_t)(growbase + r) * K + k0 + c,
                  &lds[buf * 32768 + q * 8192 + ((j * 8 + w) << 9)]);
        }
    };
    auto LDF = [&](int buf, int q, int r, int ks) -> bf16x8_t {
        const int c = (ks * 32 + fc) ^ ((r & 7) << 3);
        return *reinterpret_cast<const bf16x8_t*>(
            &lds[buf * 32768 + q * 8192 + r * 64 + c]);
    };

    f32x4_t acc[8][4] = {};
    bf16x8_t af[4][2], bA[2][2], bB[2][2];

#define MFMA_Q(mh, nh, bfr)                                                    \
    do {                                                                       \
        _Pragma("unroll")                                                      \
        for (int mi = 0; mi < 4; ++mi)                                         \
            _Pragma("unroll")                                                  \
            for (int ni = 0; ni < 2; ++ni)                                     \
                _Pragma("unroll")                                              \
                for (int ks = 0; ks < 2; ++ks)                                 \
                    acc[(mh) * 4 + mi][(nh) * 2 + ni] =                        \
                        __builtin_amdgcn_mfma_f32_16x16x32_bf16(               \
                            af[mi][ks], bfr[ni][ks],                           \
                            acc[(mh) * 4 + mi][(nh) * 2 + ni], 0, 0, 0);       \
    } while (0)

    STAGE(A, row0,       0, 0, 0);
    STAGE(A, row0 + 128, 0, 0, 1);
    STAGE(B, col0,       0, 0, 2);
    STAGE(B, col0 + 128, 0, 0, 3);
    if (NT > 1) {
        STAGE(B, col0,       64, 1, 2);
        STAGE(B, col0 + 128, 64, 1, 3);
        STAGE(A, row0,       64, 1, 0);
        asm volatile("s_waitcnt vmcnt(6)" ::: "memory");
    } else {
        asm volatile("s_waitcnt vmcnt(0)" ::: "memory");
    }
    BAR;

    for (int kt = 0; kt < NT; ++kt) {
        const int buf = kt & 1, nbuf = buf ^ 1;
        // ---- phase 0
        #pragma unroll
        for (int mi = 0; mi < 4; ++mi)
            #pragma unroll
            for (int ks = 0; ks < 2; ++ks)
                af[mi][ks] = LDF(buf, qa, mi * 16 + fr, ks);
        #pragma unroll
        for (int ni = 0; ni < 2; ++ni)
            #pragma unroll
            for (int ks = 0; ks < 2; ++ks)
                bA[ni][ks] = LDF(buf, qb, bb + ni * 16 + fr, ks);
        if (kt + 1 < NT) STAGE(A, row0 + 128, (kt + 1) << 6, nbuf, 1);
        BAR;
        __builtin_amdgcn_s_setprio(1);
        MFMA_Q(0, 0, bA);
        __builtin_amdgcn_s_setprio(0);
        BAR;
        // ---- phase 1
        #pragma unroll
        for (int ni = 0; ni < 2; ++ni)
            #pragma unroll
            for (int ks = 0; ks < 2; ++ks)
                bB[ni][ks] = LDF(buf, qb, bb + 32 + ni * 16 + fr, ks);
        BAR;
        __builtin_amdgcn_s_setprio(1);
        MFMA_Q(0, 1, bB);
        __builtin_amdgcn_s_setprio(0);
        BAR;
        // ---- phase 2
        #pragma unroll
        for (int mi = 0; mi < 4; ++mi)
            #pragma unroll
            for (int ks = 0; ks < 2; ++ks)
                af[mi][ks] = LDF(buf, qa, 64 + mi * 16 + fr, ks);
        if (kt + 2 < NT) {
            STAGE(B, col0,       (kt + 2) << 6, buf, 2);
            STAGE(B, col0 + 128, (kt + 2) << 6, buf, 3);
        }
        BAR;
        __builtin_amdgcn_s_setprio(1);
        MFMA_Q(1, 1, bB);
        __builtin_amdgcn_s_setprio(0);
        BAR;
        // ---- phase 3
        if (kt + 2 < NT) {
            STAGE(A, row0, (kt + 2) << 6, buf, 0);
            asm volatile("s_waitcnt vmcnt(6)" ::: "memory");
        } else {
            asm volatile("s_waitcnt vmcnt(0)" ::: "memory");
        }
        BAR;
        __builtin_amdgcn_s_setprio(1);
        MFMA_Q(1, 0, bA);
        __builtin_amdgcn_s_setprio(0);
        BAR;
    }
#undef MFMA_Q

    const int cr = (l >> 4) * 4;
    const int cc = l & 15;
    #pragma unroll
    for (int m = 0; m < 8; ++m) {
        #pragma unroll
        for (int n = 0; n < 4; ++n) {
            size_t base = (size_t)(row0 + wm * 128 + m * 16 + cr) * N +
                          (col0 + wn * 64 + n * 16 + cc);
            #pragma unroll
            for (int j = 0; j < 4; ++j)
                Cb[base + (size_t)j * N] = f2bf(acc[m][n][j]);
        }
    }
}

// ---------------------------------------------------------------------------
// 2b. 256x128-tile 8-phase bf16 MFMA GEMM (TN), f32 out + residual. (GEMM2)
//     BK=64, 8 waves (2Mx4N, per-wave 128x32), 3 LDS halves/K-tile
//     (A-q0, A-q1, B-q2), 96 KiB dbuf, counted vmcnt(4), XCD-chunked
//     blockIdx swizzle (grid 8x32 = 256 WGs, 32/XCD).
// ---------------------------------------------------------------------------
__global__ __launch_bounds__(512) void gemm_out(const short* __restrict__ A,
                                                const short* __restrict__ B,
                                                const float* __restrict__ add,
                                                float* __restrict__ C,
                                                int M, int N, int K) {
    __shared__ short lds[2 * 3 * 8192];   // 96 KiB

    const int tid = threadIdx.x;
    const int w = tid >> 6, l = tid & 63;

    // XCD-chunked bijective swizzle (nwg = 256, 8 XCDs, 32 WGs/chunk)
    const int id = blockIdx.y * gridDim.x + blockIdx.x;
    const int cpx = (gridDim.x * gridDim.y) >> 3;
    const int sid = (id & 7) * cpx + (id >> 3);
    const int row0 = (sid / gridDim.x) * 256;
    const int col0 = (sid % gridDim.x) * 128;

    const int wm = w >> 2;               // 0..1  (M wave; quarter qa = wm)
    const int wn = w & 3;                // 0..3  (N wave; 32 cols each)
    const int fr = l & 15;
    const int fc = (l >> 4) * 8;
    const int NT = K >> 6;
    const int bb = wn * 32;              // wave's row base within B quarter

    auto STAGE = [&](const short* __restrict__ G, int growbase, int k0,
                     int buf, int q) {
        #pragma unroll
        for (int j = 0; j < 2; ++j) {
            const int e = ((j * 8 + w) << 9) + l * 8;
            const int r = e >> 6;
            const int c = (e & 63) ^ ((r & 7) << 3);
            GLL16(G + (size_t)(growbase + r) * K + k0 + c,
                  &lds[buf * 24576 + q * 8192 + ((j * 8 + w) << 9)]);
        }
    };
    auto LDF = [&](int buf, int q, int r, int ks) -> bf16x8_t {
        const int c = (ks * 32 + fc) ^ ((r & 7) << 3);
        return *reinterpret_cast<const bf16x8_t*>(
            &lds[buf * 24576 + q * 8192 + r * 64 + c]);
    };

    f32x4_t acc[8][2] = {};
    bf16x8_t af[4][2], bA[2], bB[2];

#define MFMA_H(mh, an, bfr)                                                    \
    do {                                                                       \
        _Pragma("unroll")                                                      \
        for (int mi = 0; mi < 4; ++mi)                                         \
            _Pragma("unroll")                                                  \
            for (int ks = 0; ks < 2; ++ks)                                     \
                acc[(mh) * 4 + mi][(an)] =                                     \
                    __builtin_amdgcn_mfma_f32_16x16x32_bf16(                   \
                        af[mi][ks], bfr[ks], acc[(mh) * 4 + mi][(an)], 0, 0, 0);\
    } while (0)

    // prologue: kt0 all 3 halves (buf0); kt1 B + A-q0 (buf1)
    STAGE(A, row0,       0, 0, 0);
    STAGE(A, row0 + 128, 0, 0, 1);
    STAGE(B, col0,       0, 0, 2);
    if (NT > 1) {
        STAGE(B, col0, 64, 1, 2);
        STAGE(A, row0, 64, 1, 0);
        asm volatile("s_waitcnt vmcnt(4)" ::: "memory");
    } else {
        asm volatile("s_waitcnt vmcnt(0)" ::: "memory");
    }
    BAR;

    for (int kt = 0; kt < NT; ++kt) {
        const int buf = kt & 1, nbuf = buf ^ 1;
        // ---- phase 0: af(mh0) + bA; stage A-q1(kt+1) -> nbuf
        #pragma unroll
        for (int mi = 0; mi < 4; ++mi)
            #pragma unroll
            for (int ks = 0; ks < 2; ++ks)
                af[mi][ks] = LDF(buf, wm, mi * 16 + fr, ks);
        #pragma unroll
        for (int ks = 0; ks < 2; ++ks)
            bA[ks] = LDF(buf, 2, bb + fr, ks);
        if (kt + 1 < NT) STAGE(A, row0 + 128, (kt + 1) << 6, nbuf, 1);
        BAR;
        __builtin_amdgcn_s_setprio(1);
        MFMA_H(0, 0, bA);
        __builtin_amdgcn_s_setprio(0);
        BAR;
        // ---- phase 1: bB
        #pragma unroll
        for (int ks = 0; ks < 2; ++ks)
            bB[ks] = LDF(buf, 2, bb + 16 + fr, ks);
        BAR;
        __builtin_amdgcn_s_setprio(1);
        MFMA_H(0, 1, bB);
        __builtin_amdgcn_s_setprio(0);
        BAR;
        // ---- phase 2: af(mh1); stage B(kt+2) -> buf
        #pragma unroll
        for (int mi = 0; mi < 4; ++mi)
            #pragma unroll
            for (int ks = 0; ks < 2; ++ks)
                af[mi][ks] = LDF(buf, wm, 64 + mi * 16 + fr, ks);
        if (kt + 2 < NT) STAGE(B, col0, (kt + 2) << 6, buf, 2);
        BAR;
        __builtin_amdgcn_s_setprio(1);
        MFMA_H(1, 1, bB);
        __builtin_amdgcn_s_setprio(0);
        BAR;
        // ---- phase 3: stage A-q0(kt+2) -> buf; counted vmcnt
        if (kt + 2 < NT) {
            STAGE(A, row0, (kt + 2) << 6, buf, 0);
            asm volatile("s_waitcnt vmcnt(4)" ::: "memory");
        } else {
            asm volatile("s_waitcnt vmcnt(0)" ::: "memory");
        }
        BAR;
        __builtin_amdgcn_s_setprio(1);
        MFMA_H(1, 0, bA);
        __builtin_amdgcn_s_setprio(0);
        BAR;
    }
#undef MFMA_H

    // epilogue: f32 + residual
    const int cr = (l >> 4) * 4;
    const int cc = l & 15;
    #pragma unroll
    for (int m = 0; m < 8; ++m) {
        #pragma unroll
        for (int n = 0; n < 2; ++n) {
            size_t base = (size_t)(row0 + wm * 128 + m * 16 + cr) * N +
                          (col0 + wn * 32 + n * 16 + cc);
            #pragma unroll
            for (int j = 0; j < 4; ++j)
                C[base + (size_t)j * N] = acc[m][n][j] + add[base + (size_t)j * N];
        }
    }
}

// ---------------------------------------------------------------------------
// 3. V = x_part @ Bm^T via MFMA. One wave per 16 rows.
// ---------------------------------------------------------------------------
__global__ __launch_bounds__(64) void v_mfma(const unsigned short* __restrict__ xz,
                                             const unsigned short* __restrict__ Bmb,
                                             float* __restrict__ V) {
    const int l = threadIdx.x;
    const int r0 = blockIdx.x * 16;
    const int fr = l & 15;
    const int fk = (l >> 4) * 8;

    const unsigned short* aP = xz + (size_t)(r0 + fr) * (2 * D_INNER) + fk;
    const unsigned short* bP = Bmb + fr * D_INNER + fk;

    f32x4_t acc = {};
    #pragma unroll 4
    for (int k0 = 0; k0 < D_INNER; k0 += 32) {
        bf16x8_t a = *reinterpret_cast<const bf16x8_t*>(aP + k0);
        bf16x8_t b = *reinterpret_cast<const bf16x8_t*>(bP + k0);
        acc = __builtin_amdgcn_mfma_f32_16x16x32_bf16(a, b, acc, 0, 0, 0);
    }

    const int cr = (l >> 4) * 4;
    const int cc = l & 15;
    #pragma unroll
    for (int j = 0; j < 4; ++j)
        V[(size_t)(r0 + cr + j) * D_STATE + cc] = acc[j];
}

// ---------------------------------------------------------------------------
// 4a. check_a: flag = (A != I) ? 1 : 0
// ---------------------------------------------------------------------------
__global__ __launch_bounds__(256) void check_a(const float* __restrict__ A,
                                               int* __restrict__ flag) {
    const int i = threadIdx.x;
    if (i == 0) *flag = 0;
    __syncthreads();
    const float ex = ((i >> 4) == (i & 15)) ? 1.0f : 0.0f;
    unsigned long long bad = __ballot(A[i] != ex);
    if ((i & 63) == 0 && bad) atomicOr(flag, 1);
}

// ---------------------------------------------------------------------------
// 4b. Parallel inclusive cumsum over t (A == I path).
// ---------------------------------------------------------------------------
__global__ __launch_bounds__(256) void scan_par(const float* __restrict__ V,
                                                float* __restrict__ S,
                                                const int* __restrict__ flag) {
    if (*flag) return;
    const int p = blockIdx.x;        // 0..31
    const int b = p >> 4, s = p & 15;
    const int tid = threadIdx.x;
    const float* vb = V + (size_t)b * SEQ * D_STATE + s;
    float* sb = S + (size_t)b * SEQ * D_STATE + s;

    const int t0 = tid * 16;
    float v[16];
    float run = 0.0f;
    #pragma unroll
    for (int j = 0; j < 16; ++j) {
        run += vb[(size_t)(t0 + j) * D_STATE];
        v[j] = run;
    }

    const float tot = run;
    float sc = tot;
    #pragma unroll
    for (int off = 1; off < 64; off <<= 1) {
        float n = __shfl_up(sc, off, 64);
        if ((tid & 63) >= off) sc += n;
    }
    __shared__ float wtot[4];
    if ((tid & 63) == 63) wtot[tid >> 6] = sc;
    __syncthreads();
    float woff = 0.0f;
    #pragma unroll
    for (int w2 = 0; w2 < 4; ++w2)
        if (w2 < (tid >> 6)) woff += wtot[w2];
    const float excl = sc - tot + woff;

    #pragma unroll
    for (int j = 0; j < 16; ++j)
        sb[(size_t)(t0 + j) * D_STATE] = v[j] + excl;
}

// ---------------------------------------------------------------------------
// 4c. Sequential general-A scan (fallback; no-op when A == I)
// ---------------------------------------------------------------------------
#define SCAN_CHUNK 256

__global__ __launch_bounds__(64) void scan_seq(const float* __restrict__ V,
                                               const float* __restrict__ A,
                                               float* __restrict__ S,
                                               const int* __restrict__ flag) {
    if (*flag == 0) return;
    __shared__ float Al[D_STATE * D_STATE];
    __shared__ float Vl[2 * SCAN_CHUNK * D_STATE];
    __shared__ float Sl[2 * SCAN_CHUNK * D_STATE];

    const int tid = threadIdx.x;
    for (int i = tid; i < D_STATE * D_STATE; i += 64) Al[i] = A[i];
    __syncthreads();

    float st = 0.0f;
    const int bb = (tid >> 4) & 1;
    const int ss = tid & 15;

    for (int t0 = 0; t0 < SEQ; t0 += SCAN_CHUNK) {
        for (int idx = tid; idx < 2 * SCAN_CHUNK * D_STATE; idx += 64) {
            int b = idx >> 12;
            int rem = idx & 4095;
            Vl[idx] = V[((size_t)(b * SEQ + t0) * D_STATE) + rem];
        }
        __syncthreads();

        if (tid < 32) {
            float* vb = Vl + bb * SCAN_CHUNK * D_STATE + ss;
            float* sb = Sl + bb * SCAN_CHUNK * D_STATE + ss;
            for (int t = 0; t < SCAN_CHUNK; ++t) {
                float ns = vb[t * D_STATE];
                #pragma unroll
                for (int s2 = 0; s2 < D_STATE; ++s2) {
                    float other = __shfl(st, (tid & 16) | s2, 64);
                    ns = fmaf(Al[ss * D_STATE + s2], other, ns);
                }
                st = ns;
                sb[t * D_STATE] = st;
            }
        }
        __syncthreads();

        for (int idx = tid; idx < 2 * SCAN_CHUNK * D_STATE; idx += 64) {
            int b = idx >> 12;
            int rem = idx & 4095;
            S[((size_t)(b * SEQ + t0) * D_STATE) + rem] = Sl[idx];
        }
        __syncthreads();
    }
}

// ---------------------------------------------------------------------------
// 5. y = (silu(conv(x_part)) + S @ Cm) * sigmoid(z)  -> bf16 output
// ---------------------------------------------------------------------------
__global__ __launch_bounds__(256) void y_kernel(const unsigned short* __restrict__ xz,
                                                const float* __restrict__ S,
                                                const float* __restrict__ Cm,
                                                const float* __restrict__ convw,
                                                const float* __restrict__ convb,
                                                unsigned short* __restrict__ y) {
    const int tid = threadIdx.x;
    const int i0 = blockIdx.x * 512 + tid * 2;
    const int r0 = blockIdx.y * 64;
    const int tb0 = r0 & (SEQ - 1);

    const float4 w0 = *reinterpret_cast<const float4*>(&convw[i0 * D_CONV]);
    const float4 w1 = *reinterpret_cast<const float4*>(&convw[(i0 + 1) * D_CONV]);
    const float cb0 = convb[i0], cb1 = convb[i0 + 1];
    float cm0[D_STATE], cm1[D_STATE];
    #pragma unroll
    for (int s = 0; s < D_STATE; ++s) {
        float2 c = *reinterpret_cast<const float2*>(&Cm[s * D_INNER + i0]);
        cm0[s] = c.x; cm1[s] = c.y;
    }

    float2 xm1 = make_float2(0.f, 0.f), xm2 = xm1, xm3 = xm1;
    if (tb0 >= 1) { ushort2 u = *reinterpret_cast<const ushort2*>(&xz[(size_t)(r0 - 1) * (2 * D_INNER) + i0]); xm1 = make_float2(bf2f(u.x), bf2f(u.y)); }
    if (tb0 >= 2) { ushort2 u = *reinterpret_cast<const ushort2*>(&xz[(size_t)(r0 - 2) * (2 * D_INNER) + i0]); xm2 = make_float2(bf2f(u.x), bf2f(u.y)); }
    if (tb0 >= 3) { ushort2 u = *reinterpret_cast<const ushort2*>(&xz[(size_t)(r0 - 3) * (2 * D_INNER) + i0]); xm3 = make_float2(bf2f(u.x), bf2f(u.y)); }

    for (int r = r0; r < r0 + 64; ++r) {
        const ushort2 xu = *reinterpret_cast<const ushort2*>(&xz[(size_t)r * (2 * D_INNER) + i0]);
        const ushort2 zu = *reinterpret_cast<const ushort2*>(&xz[(size_t)r * (2 * D_INNER) + D_INNER + i0]);
        const float2 x0 = make_float2(bf2f(xu.x), bf2f(xu.y));

        float a0 = cb0;
        a0 = fmaf(w0.x, xm3.x, a0); a0 = fmaf(w0.y, xm2.x, a0);
        a0 = fmaf(w0.z, xm1.x, a0); a0 = fmaf(w0.w, x0.x, a0);
        float a1 = cb1;
        a1 = fmaf(w1.x, xm3.y, a1); a1 = fmaf(w1.y, xm2.y, a1);
        a1 = fmaf(w1.z, xm1.y, a1); a1 = fmaf(w1.w, x0.y, a1);

        const float xc0 = a0 / (1.0f + expf(-a0));
        const float xc1 = a1 / (1.0f + expf(-a1));

        const float4* Sp = reinterpret_cast<const float4*>(S + (size_t)r * D_STATE);
        const float4 s0 = Sp[0], s1 = Sp[1], s2 = Sp[2], s3 = Sp[3];
        const float sv[D_STATE] = {s0.x, s0.y, s0.z, s0.w, s1.x, s1.y, s1.z, s1.w,
                                   s2.x, s2.y, s2.z, s2.w, s3.x, s3.y, s3.z, s3.w};
        float sc0 = 0.f, sc1 = 0.f;
        #pragma unroll
        for (int s = 0; s < D_STATE; ++s) {
            sc0 = fmaf(sv[s], cm0[s], sc0);
            sc1 = fmaf(sv[s], cm1[s], sc1);
        }

        const float z0 = bf2f(zu.x), z1 = bf2f(zu.y);
        const float g0 = 1.0f / (1.0f + expf(-z0));
        const float g1 = 1.0f / (1.0f + expf(-z1));

        ushort2 o;
        o.x = f2bf((xc0 + sc0) * g0);
        o.y = f2bf((xc1 + sc1) * g1);
        *reinterpret_cast<ushort2*>(&y[(size_t)r * D_INNER + i0]) = o;

        xm3 = xm2; xm2 = xm1; xm1 = x0;
    }
}

// ---------------------------------------------------------------------------
// launch
// ---------------------------------------------------------------------------
extern "C" void kernel_launch(void* const* d_in, const int* in_sizes, int n_in,
                              void* d_out, int out_size, void* d_ws, size_t ws_size,
                              hipStream_t stream) {
    const float* x      = (const float*)d_in[0];
    const float* ln_g   = (const float*)d_in[1];
    const float* ln_b   = (const float*)d_in[2];
    const float* W_in   = (const float*)d_in[3];
    const float* conv_w = (const float*)d_in[4];
    const float* conv_b = (const float*)d_in[5];
    const float* W_out  = (const float*)d_in[6];
    const float* A      = (const float*)d_in[7];
    const float* Bm     = (const float*)d_in[8];
    const float* Cm     = (const float*)d_in[9];
    float* out = (float*)d_out;

    // workspace layout
    float* ws = (float*)d_ws;
    float* V  = ws;                                        // 8192*16 f32
    float* S  = V + (size_t)NROW * D_STATE;                // 8192*16 f32
    int*   flag = (int*)(S + (size_t)NROW * D_STATE);
    unsigned short* xz_bf  = (unsigned short*)(flag + 64); // 8192*4096 bf16
    unsigned short* xn_bf  = xz_bf  + (size_t)NROW * 2 * D_INNER;
    unsigned short* Win_bf = xn_bf  + (size_t)NROW * D_MODEL;
    unsigned short* Wout_bf= Win_bf + (size_t)(2 * D_INNER) * D_MODEL;
    unsigned short* Bm_bf  = Wout_bf + (size_t)D_MODEL * D_INNER;
    unsigned short* y_bf   = Bm_bf  + (size_t)D_STATE * D_INNER;

    // weight conversions (one launch; 6324224 elems / 8 / 256 = 3088 blocks)
    cvt_all<<<3088, 256, 0, stream>>>(W_in, W_out, Bm, Win_bf, Wout_bf, Bm_bf);

    // 1. LayerNorm -> bf16
    ln_kernel<<<NROW, 256, 0, stream>>>(x, ln_g, ln_b, xn_bf);

    // 2. xz = xn @ W_in^T -> bf16   (M=8192, N=4096, K=1024), 8-phase 256^2
    gemm256_bf16<<<dim3((2 * D_INNER) / 256, NROW / 256), 512, 0, stream>>>(
        (const short*)xn_bf, (const short*)Win_bf, xz_bf,
        NROW, 2 * D_INNER, D_MODEL);

    // 3. V = x_part @ Bm^T  (MFMA, one wave / 16 rows)
    v_mfma<<<NROW / 16, 64, 0, stream>>>(xz_bf, Bm_bf, V);

    // 4. scan: parallel cumsum when A==I, sequential general fallback otherwise
    check_a<<<1, 256, 0, stream>>>(A, flag);
    scan_par<<<32, 256, 0, stream>>>(V, S, flag);
    scan_seq<<<1, 64, 0, stream>>>(V, A, S, flag);

    // 5. y = (silu(conv(x_part)) + S@Cm) * sigmoid(z) -> bf16
    y_kernel<<<dim3(D_INNER / 512, NROW / 64), 256, 0, stream>>>(
        xz_bf, S, Cm, conv_w, conv_b, y_bf);

    // 6. out = x + y @ W_out^T  (M=8192, N=1024, K=2048), 8-phase 256x128
    gemm_out<<<dim3(D_MODEL / 128, NROW / 256), 512, 0, stream>>>(
        (const short*)y_bf, (const short*)Wout_bf, x, out,
        NROW, D_MODEL, D_INNER);
}